// Round 5
// baseline (597.176 us; speedup 1.0000x reference)
//
#include <hip/hip_runtime.h>
#include <cstdint>
#include <cmath>

// Problem constants: B=2, F=5, C=256, H=64, W=64, HN=8, hd=16
// Token layout: n = (b*5+f)*4096 + h*64 + w, N = 40960 tokens, channels-last.

typedef __bf16 bf16x8 __attribute__((ext_vector_type(8)));
typedef float f32x4 __attribute__((ext_vector_type(4)));

__device__ __forceinline__ unsigned short f2bf(float f) {
    union { float f; unsigned int u; } v; v.f = f;
    unsigned int r = (v.u + 0x7fffu + ((v.u >> 16) & 1u)) >> 16;
    return (unsigned short)r;
}
__device__ __forceinline__ float bf2f(unsigned short h) {
    union { unsigned int u; float f; } v; v.u = ((unsigned int)h) << 16;
    return v.f;
}
// tanh-form GELU, fully inline
__device__ __forceinline__ float gelu_fast(float x) {
    float z2 = 2.8853900817779268f * x * (0.7978845608028654f + 0.0356774081363001f * x * x);
    float u = __builtin_amdgcn_exp2f(z2);
    return x - x * __builtin_amdgcn_rcpf(1.0f + u);
}

// async global->LDS, 16B per lane; LDS dest = wave-uniform base + lane*16
__device__ __forceinline__ void gld16(const unsigned short* g, unsigned short* l) {
    __builtin_amdgcn_global_load_lds(
        (const __attribute__((address_space(1))) void*)g,
        (__attribute__((address_space(3))) void*)l, 16, 0, 0);
}

// ---------------- weight convert: wh/wv/wf row-major bf16; w1/w2 MFMA-fragment-major ----------------
// R3 postmortem: per-lane weight-fragment loads (16-row stride-512B scatter) were the FFN
// latency killer. w1p/w2p are packed so each fragment is a CONTIGUOUS 1KB block: lane l's
// 16B at [frag*1024 + l*16]. One coalesced wave-load per fragment, pure L2 streaming.
//   w1p frag id: ((g*4 + fi)*8 + ks)  g=hid-ch/64, fi=16-row group, ks=k/32  (row=g*64+fi*16+r16, k=ks*32+kg*8)
//   w2p frag id: (cg*32 + ksg)        cg=outcol/16, ksg=k/32                (row=cg*16+r16,      k=ksg*32+kg*8)
__global__ __launch_bounds__(256) void cvt_all_kernel(
        const float* __restrict__ wh, const float* __restrict__ wv,
        const float* __restrict__ wf, const float* __restrict__ w1,
        const float* __restrict__ w2,
        unsigned short* __restrict__ whb, unsigned short* __restrict__ wvb,
        unsigned short* __restrict__ wfb, unsigned short* __restrict__ w1b,
        unsigned short* __restrict__ w2b) {
    int i = blockIdx.x * 256 + threadIdx.x;   // grid covers 229376 exactly
    if (i < 163840) {
        const float* s; unsigned short* d; int j;
        if (i < 49152)      { s = wh; d = whb; j = i; }
        else if (i < 98304) { s = wv; d = wvb; j = i - 49152; }
        else                { s = wf; d = wfb; j = i - 98304; }
        d[j] = f2bf(s[j]);
    } else if (i < 196608) {
        int t = i - 163840;                   // 32768 threads x 8 elements
        int lane = t & 63, ks = (t >> 6) & 7, fi = (t >> 9) & 3, g = t >> 11;
        int row = g * 64 + fi * 16 + (lane & 15);
        int k0 = ks * 32 + (lane >> 4) * 8;
        const float* s = w1 + (size_t)row * 256 + k0;
        unsigned short o[8];
        #pragma unroll
        for (int e = 0; e < 8; ++e) o[e] = f2bf(s[e]);
        *(uint4*)&w1b[(size_t)t * 8] = *(const uint4*)o;
    } else {
        int u = i - 196608;                   // 32768 threads x 8 elements
        int lane = u & 63, ksg = (u >> 6) & 31, cg = u >> 11;
        int row = cg * 16 + (lane & 15);
        int k0 = ksg * 32 + (lane >> 4) * 8;
        const float* s = w2 + (size_t)row * 1024 + k0;
        unsigned short o[8];
        #pragma unroll
        for (int e = 0; e < 8; ++e) o[e] = f2bf(s[e]);
        *(uint4*)&w2b[(size_t)u * 8] = *(const uint4*)o;
    }
}

// ---------------- fused LN1 + QKV(h&v): one block per (bf, h) line (64 tokens) ----------------
__global__ __launch_bounds__(256) void ln1qkv_kernel(
        const float* __restrict__ x,
        const float* __restrict__ g, const float* __restrict__ bta,
        const unsigned short* __restrict__ whb, const float* __restrict__ bh,
        const unsigned short* __restrict__ wvb, const float* __restrict__ bv,
        unsigned short* __restrict__ xt,
        unsigned short* __restrict__ qkvh, unsigned short* __restrict__ qkvv) {
    __shared__ __align__(16) unsigned short At[64 * 264];   // 33792 B, [token][ch] padded
    __shared__ __align__(16) unsigned short Bs[128 * 64];   // 16384 B, one BK=64 B-tile
    __shared__ float psum[4][64], psq[4][64], meanL[64], rstdL[64];
    __shared__ float gg[256], bb[256];

    int bx = blockIdx.x;
    int bf = bx >> 6, h = bx & 63;
    size_t base = (size_t)bf * 1048576 + (size_t)h * 64;
    int tid = threadIdx.x;
    int w = tid & 63, cg = tid >> 6;
    float s = 0.f, sq = 0.f;
    for (int k = 0; k < 64; ++k) {
        int c = cg * 64 + k;
        float v = x[base + (size_t)c * 4096 + w];
        s += v; sq += v * v;
        At[w * 264 + c] = f2bf(v);
    }
    psum[cg][w] = s; psq[cg][w] = sq;
    gg[tid] = g[tid]; bb[tid] = bta[tid];
    __syncthreads();
    if (tid < 64) {
        float ss = psum[0][tid] + psum[1][tid] + psum[2][tid] + psum[3][tid];
        float qq = psq[0][tid] + psq[1][tid] + psq[2][tid] + psq[3][tid];
        float mean = ss * (1.f / 256.f);
        float var = qq * (1.f / 256.f) - mean * mean;
        meanL[tid] = mean;
        rstdL[tid] = rsqrtf(var + 1e-5f);
    }
    __syncthreads();
    int n0g = bf * 4096 + h * 64;
    for (int t = 0; t < 8; ++t) {
        int idx = t * 256 + tid;
        int tok = idx >> 5, cc = idx & 31;
        unsigned short raw[8];
        *(uint4*)raw = *(const uint4*)&At[tok * 264 + cc * 8];
        *(uint4*)&xt[(size_t)(n0g + tok) * 256 + cc * 8] = *(const uint4*)raw;
        float mean = meanL[tok], rstd = rstdL[tok];
        unsigned short nm[8];
        #pragma unroll
        for (int e = 0; e < 8; ++e) {
            int ch = cc * 8 + e;
            nm[e] = f2bf((bf2f(raw[e]) - mean) * rstd * gg[ch] + bb[ch]);
        }
        *(uint4*)&At[tok * 264 + cc * 8] = *(const uint4*)nm;
    }
    __syncthreads();

    int lane = tid & 63, wvid = tid >> 6;
    int r16 = lane & 15, kg = lane >> 4;
    int srow = wvid * 8 + (lane >> 3);
    int segg = (lane & 7) ^ (lane >> 3);
    unsigned short* lB = Bs + wvid * 512;
    for (int t = 0; t < 6; ++t) {
        const unsigned short* Wt; const float* bias; unsigned short* dst; int ot, aoff;
        if (t < 3) { Wt = whb + t * 16384;       bias = bh + t * 128;       dst = qkvh; ot = t * 128;       aoff = 0; }
        else       { Wt = wvb + (t - 3) * 16384; bias = bv + (t - 3) * 128; dst = qkvv; ot = (t - 3) * 128; aoff = 128; }
        f32x4 acc[4][2] = {};
        for (int kk = 0; kk < 2; ++kk) {
            const unsigned short* pB = Wt + (size_t)srow * 128 + kk * 64 + segg * 8;
            #pragma unroll
            for (int i = 0; i < 4; ++i)
                gld16(pB + (size_t)i * 32 * 128, lB + i * 2048);
            __syncthreads();
            #pragma unroll
            for (int tt = 0; tt < 2; ++tt) {
                int ka = aoff + kk * 64 + (tt * 4 + kg) * 8;
                int ss = ((tt * 4 + kg) ^ (r16 & 7)) * 8;
                bf16x8 af[4], bfr[2];
                #pragma unroll
                for (int i = 0; i < 4; ++i)
                    af[i] = *(const bf16x8*)&At[(i * 16 + r16) * 264 + ka];
                #pragma unroll
                for (int j = 0; j < 2; ++j)
                    bfr[j] = *(const bf16x8*)&Bs[(wvid * 32 + j * 16 + r16) * 64 + ss];
                #pragma unroll
                for (int i = 0; i < 4; ++i)
                    #pragma unroll
                    for (int j = 0; j < 2; ++j)
                        acc[i][j] = __builtin_amdgcn_mfma_f32_16x16x32_bf16(af[i], bfr[j], acc[i][j], 0, 0, 0);
            }
            __syncthreads();
        }
        float biasv[2];
        #pragma unroll
        for (int j = 0; j < 2; ++j) biasv[j] = bias[wvid * 32 + j * 16 + r16];
        #pragma unroll
        for (int i = 0; i < 4; ++i)
            #pragma unroll
            for (int j = 0; j < 2; ++j)
                #pragma unroll
                for (int r = 0; r < 4; ++r) {
                    int m = i * 16 + kg * 4 + r;
                    int nc = ot + wvid * 32 + j * 16 + r16;
                    dst[(size_t)(n0g + m) * 384 + nc] = f2bf(acc[i][j][r] + biasv[j]);
                }
    }
}

// ---------------- templated MFMA GEMM (only MODE 4 = proj+LN2 instantiated) ----------------
// MODE 4 now writes C2 (tn) in FRAGMENT-MAJOR layout (R4): tnb[((line*32 + jj*8 + ks)*64
// + kgc*16 + r16r)*8 + e] holds tn[line*64 + jj*16 + r16r][ks*32 + kgc*8 + e], so the FFN
// kernel's phase-1 B-fragments are lane-linear 1KB wave-loads (no LDS staging needed).
// NOTE: every acc[] subscript must be compile-time constant (dynamic indexing
// spills the whole accumulator array to scratch -- R8 postmortem: 1.36 GB scratch traffic).
template<int BM, int BN, int MODE, int MINW>
__global__ __launch_bounds__(256, MINW) void gemm_t(
        const unsigned short* __restrict__ A, int lda,
        const unsigned short* __restrict__ B,
        const float* __restrict__ bias,
        unsigned short* __restrict__ C, int ldc,
        const unsigned short* __restrict__ res,
        float* __restrict__ outT,
        int K,
        const float* __restrict__ g2, const float* __restrict__ b2,
        unsigned short* __restrict__ C2) {
    constexpr int WCOL = BN / 4;        // cols per wave
    constexpr int MR = BM / 16;         // 16-row fragments per wave
    constexpr int NR = WCOL / 16;       // 16-col fragments per wave
    constexpr int AG = BM / 32;         // A gld16 per wave per K-step
    constexpr int BG = BN / 32;         // B gld16 per wave per K-step
    __shared__ __align__(16) unsigned char smem[(BM + BN) * 128];
    unsigned short* As = (unsigned short*)smem;
    unsigned short* Bs = (unsigned short*)(smem + BM * 128);

    int tid = threadIdx.x;
    int lane = tid & 63, wvid = tid >> 6;
    int r16 = lane & 15, kg = lane >> 4;

    // XCD-aware remap (total blocks divisible by 8 in all configs)
    int nx = gridDim.x;
    int L = blockIdx.y * nx + blockIdx.x;
    int T = nx * gridDim.y;
    int newL = (T & 7) ? L : ((L & 7) * (T >> 3) + (L >> 3));
    int nt = newL % nx, mt = newL / nx;
    int m0 = mt * BM, n0 = nt * BN;

    int srow = wvid * 8 + (lane >> 3);
    int segg = (lane & 7) ^ (lane >> 3);
    const unsigned short* pA = A + (size_t)(m0 + srow) * lda + segg * 8;
    const unsigned short* pB = B + (size_t)(n0 + srow) * K + segg * 8;
    unsigned short* lA = As + wvid * 512;
    unsigned short* lB = Bs + wvid * 512;

    f32x4 acc[MR][NR] = {};
    for (int k0 = 0; k0 < K; k0 += 64) {
        #pragma unroll
        for (int i = 0; i < AG; ++i)
            gld16(pA + (size_t)i * 32 * lda, lA + i * 2048);
        #pragma unroll
        for (int i = 0; i < BG; ++i)
            gld16(pB + (size_t)i * 32 * K, lB + i * 2048);
        pA += 64; pB += 64;
        __syncthreads();
        #pragma unroll
        for (int t = 0; t < 2; ++t) {
            bf16x8 af[MR], bfr[NR];
            int ss = ((t * 4 + kg) ^ (r16 & 7)) * 8;
            #pragma unroll
            for (int i = 0; i < MR; ++i)
                af[i] = *(const bf16x8*)&As[(i * 16 + r16) * 64 + ss];
            #pragma unroll
            for (int j = 0; j < NR; ++j)
                bfr[j] = *(const bf16x8*)&Bs[(wvid * WCOL + j * 16 + r16) * 64 + ss];
            #pragma unroll
            for (int i = 0; i < MR; ++i)
                #pragma unroll
                for (int j = 0; j < NR; ++j)
                    acc[i][j] = __builtin_amdgcn_mfma_f32_16x16x32_bf16(af[i], bfr[j], acc[i][j], 0, 0, 0);
        }
        __syncthreads();
    }

    if constexpr (MODE == 4) {
        // BM=32, BN=256: y = acc + bias + res -> C (yb); row LN over 256 cols -> C2 (tn, frag-major)
        float* ssum = (float*)smem;             // [BM][4]
        float* ssq  = ssum + BM * 4;
        float biasv[NR];
        #pragma unroll
        for (int j = 0; j < NR; ++j) biasv[j] = bias[n0 + wvid * WCOL + j * 16 + r16];
        const unsigned short* resp = res + (size_t)m0 * 256 + wvid * WCOL;
        #pragma unroll
        for (int i = 0; i < MR; ++i)
            #pragma unroll
            for (int r = 0; r < 4; ++r) {
                int row = i * 16 + kg * 4 + r;
                #pragma unroll
                for (int j = 0; j < NR; ++j) {
                    float v = acc[i][j][r] + biasv[j] + bf2f(resp[(size_t)row * 256 + j * 16 + r16]);
                    acc[i][j][r] = v;
                    C[(size_t)(m0 + row) * 256 + wvid * WCOL + j * 16 + r16] = f2bf(v);
                }
            }
        #pragma unroll
        for (int i = 0; i < MR; ++i)
            #pragma unroll
            for (int r = 0; r < 4; ++r) {
                float s = 0.f, sq = 0.f;
                #pragma unroll
                for (int j = 0; j < NR; ++j) { float v = acc[i][j][r]; s += v; sq += v * v; }
                s += __shfl_xor(s, 1); sq += __shfl_xor(sq, 1);
                s += __shfl_xor(s, 2); sq += __shfl_xor(sq, 2);
                s += __shfl_xor(s, 4); sq += __shfl_xor(sq, 4);
                s += __shfl_xor(s, 8); sq += __shfl_xor(sq, 8);
                if (r16 == 0) {
                    int mr = i * 16 + kg * 4 + r;
                    ssum[mr * 4 + wvid] = s;
                    ssq[mr * 4 + wvid] = sq;
                }
            }
        __syncthreads();
        float g2v[NR], b2v[NR];
        #pragma unroll
        for (int j = 0; j < NR; ++j) {
            g2v[j] = g2[wvid * WCOL + j * 16 + r16];
            b2v[j] = b2[wvid * WCOL + j * 16 + r16];
        }
        #pragma unroll
        for (int i = 0; i < MR; ++i)
            #pragma unroll
            for (int r = 0; r < 4; ++r) {
                int mr = i * 16 + kg * 4 + r;
                float sum = ssum[mr * 4] + ssum[mr * 4 + 1] + ssum[mr * 4 + 2] + ssum[mr * 4 + 3];
                float sq  = ssq[mr * 4] + ssq[mr * 4 + 1] + ssq[mr * 4 + 2] + ssq[mr * 4 + 3];
                float mean = sum * (1.f / 256.f);
                float var = sq * (1.f / 256.f) - mean * mean;
                float rstd = rsqrtf(var + 1e-5f);
                int row = m0 + mr;
                size_t lbase = (((size_t)(row >> 6)) * 32 + (size_t)(((row & 63) >> 4) * 8));
                #pragma unroll
                for (int j = 0; j < NR; ++j) {
                    float tv = (acc[i][j][r] - mean) * rstd * g2v[j] + b2v[j];
                    int col = wvid * WCOL + j * 16 + r16;
                    // frag-major store: frag (jj, ks), lane kgc*16+r16r, elem e
                    C2[((lbase + (col >> 5)) * 64 + ((col >> 3) & 3) * 16 + (row & 15)) * 8 + (col & 7)] = f2bf(tv);
                }
            }
    }
}

// ---------------- fused FFN v3: no tn staging (frag-major tnb), hid-only LDS ----------------
// R4 postmortem: 64KB LDS capped at 2 blocks/CU; barrier-boundary weight-load latency with
// only 4 waves/SIMD -> MfmaUtil 17%. Fix: tnb is now written frag-major by gemm_t mode 4,
// so phase-1 B-fragments are lane-linear loads from L1 (line's tn = 32KB = L1-resident).
// tnL and its staging barrier are GONE; LDS = hidL 32KB -> 4 blocks/CU, 8 waves/SIMD
// (launch_bounds(512,8) pins VGPR<=64 -- currently exactly 64). Occupancy does the hiding.
__global__ __launch_bounds__(512, 8) void ffn_fused_kernel(
        const unsigned short* __restrict__ tnb,   // frag-major per line: [line][32 frags][64 lanes][8]
        const unsigned short* __restrict__ w1p,   // frag-major, see cvt
        const float* __restrict__ b1,
        const unsigned short* __restrict__ w2p,   // frag-major, see cvt
        const float* __restrict__ b2,
        const unsigned short* __restrict__ yb,    // residual [40960][256] bf16
        float* __restrict__ outT) {               // (B,F,C,H,W) fp32
    __shared__ __align__(16) unsigned short hidL[64 * 256];  // 32KB, frag-major [ks*4+i][lane][8]

    int tid = threadIdx.x;
    int lane = tid & 63, wv = tid >> 6;           // 8 waves
    int r16 = lane & 15, kg = lane >> 4;

    // XCD-aware remap: 640 blocks, 80 per XCD contiguous
    int L = blockIdx.x;
    int blk = (L & 7) * 80 + (L >> 3);
    int m0 = blk * 64;                            // one (bf,h) line of 64 tokens

    const unsigned short* tp = tnb + (size_t)blk * 16384;   // this line's 32 tn fragments

    f32x4 acc2[4][2] = {};                        // out tile: 64 tok x 32 cols (cols wv*32..)

    for (int c = 0; c < 4; ++c) {                 // hid chunks of 256 channels
        // ---- phase 1: hid chunk ch = c*256 + wv*32 + i'*16 + (kg*4+r), tok = j*16+r16 ----
        f32x4 acc[2][4] = {};
        {
            int g = c * 4 + (wv >> 1);
            const unsigned short* ap = w1p + ((size_t)((g * 4 + (wv & 1) * 2) * 8) * 64 + lane) * 8;
            #pragma unroll
            for (int ks = 0; ks < 8; ++ks) {
                bf16x8 a0 = *(const bf16x8*)(ap + (size_t)ks * 512);
                bf16x8 a1 = *(const bf16x8*)(ap + (size_t)4096 + ks * 512);
                bf16x8 b[4];
                #pragma unroll
                for (int j = 0; j < 4; ++j)
                    b[j] = *(const bf16x8*)(tp + ((j * 8 + ks) * 64 + lane) * 8);
                #pragma unroll
                for (int j = 0; j < 4; ++j) {
                    acc[0][j] = __builtin_amdgcn_mfma_f32_16x16x32_bf16(a0, b[j], acc[0][j], 0, 0, 0);
                    acc[1][j] = __builtin_amdgcn_mfma_f32_16x16x32_bf16(a1, b[j], acc[1][j], 0, 0, 0);
                }
            }
        }
        // bias + GELU + pack 4 consecutive ch -> 8B frag-major write (4-way = write floor)
        #pragma unroll
        for (int ip = 0; ip < 2; ++ip) {
            int ch0 = c * 256 + wv * 32 + ip * 16 + kg * 4;
            float bb0 = b1[ch0], bb1 = b1[ch0 + 1], bb2 = b1[ch0 + 2], bb3 = b1[ch0 + 3];
            #pragma unroll
            for (int j = 0; j < 4; ++j) {
                float g0 = gelu_fast(acc[ip][j][0] + bb0);
                float g1 = gelu_fast(acc[ip][j][1] + bb1);
                float g2 = gelu_fast(acc[ip][j][2] + bb2);
                float g3 = gelu_fast(acc[ip][j][3] + bb3);
                uint2 pk;
                pk.x = (unsigned int)f2bf(g0) | ((unsigned int)f2bf(g1) << 16);
                pk.y = (unsigned int)f2bf(g2) | ((unsigned int)f2bf(g3) << 16);
                unsigned int hb = (((unsigned int)(wv * 4 + j) * 64 +
                                    (ip * 2 + (kg >> 1)) * 16 + r16) << 4) + ((kg & 1) << 3);
                *(uint2*)((char*)hidL + hb) = pk;
            }
        }
        __syncthreads();
        // ---- phase 2: acc2 += hid_chunk @ w2^T (A from LDS linear, B from w2p L2 stream) ----
        {
            const unsigned short* bp0 = w2p + ((size_t)((wv * 2) * 32 + c * 8) * 64 + lane) * 8;
            const unsigned short* bp1 = w2p + ((size_t)((wv * 2 + 1) * 32 + c * 8) * 64 + lane) * 8;
            #pragma unroll
            for (int ks = 0; ks < 8; ++ks) {
                bf16x8 a[4];
                #pragma unroll
                for (int i = 0; i < 4; ++i)
                    a[i] = *(const bf16x8*)&hidL[((ks * 4 + i) * 64 + lane) * 8];
                bf16x8 b0 = *(const bf16x8*)(bp0 + (size_t)ks * 512);
                bf16x8 b1v = *(const bf16x8*)(bp1 + (size_t)ks * 512);
                #pragma unroll
                for (int i = 0; i < 4; ++i) {
                    acc2[i][0] = __builtin_amdgcn_mfma_f32_16x16x32_bf16(a[i], b0, acc2[i][0], 0, 0, 0);
                    acc2[i][1] = __builtin_amdgcn_mfma_f32_16x16x32_bf16(a[i], b1v, acc2[i][1], 0, 0, 0);
                }
            }
        }
        __syncthreads();
    }

    // ---- epilogue: + b2 + yb residual, fp32 transposed store (hidL dead -> reuse as fl) ----
    float* fl = (float*)hidL;                     // [64 tokens][64 ch] fp32, XOR col swizzle (16KB)
    int bfi = m0 >> 12;
    int hh = (m0 >> 6) & 63;
    #pragma unroll
    for (int p = 0; p < 4; ++p) {                 // channel groups of 64 = waves {2p, 2p+1}
        __syncthreads();
        if ((wv >> 1) == p) {
            #pragma unroll
            for (int i = 0; i < 4; ++i)
                #pragma unroll
                for (int j = 0; j < 2; ++j)
                    #pragma unroll
                    for (int r = 0; r < 4; ++r) {
                        int ml = i * 16 + kg * 4 + r;            // token within line
                        int nl = (wv & 1) * 32 + j * 16 + r16;   // channel within group
                        int n = p * 64 + nl;
                        float v = acc2[i][j][r] + b2[n] + bf2f(yb[(size_t)(m0 + ml) * 256 + n]);
                        fl[ml * 64 + (nl ^ ml)] = v;
                    }
        }
        __syncthreads();
        for (int r = wv; r < 64; r += 8) {
            outT[(size_t)bfi * 1048576 + (size_t)(p * 64 + r) * 4096 +
                 (size_t)hh * 64 + lane] = fl[lane * 64 + (r ^ lane)];
        }
    }
}

// ---------------- attention (both directions, one launch): per (dir, b, head, line) ----------------
__global__ __launch_bounds__(256) void attn_kernel(const unsigned short* __restrict__ qkvH,
                                                   const unsigned short* __restrict__ qkvV,
                                                   unsigned short* __restrict__ ao) {
    __shared__ unsigned short qL[5 * 1024], kL[5 * 1024], vL[5 * 1024];
    __shared__ float sL[25];
    int g = blockIdx.x;
    int vertical = g >> 10;
    const unsigned short* qkv = vertical ? qkvV : qkvH;
    int lw = g & 63;
    int head = (g >> 6) & 7;
    int b = (g >> 9) & 1;
    int tid = threadIdx.x;
    for (int c = tid; c < 640; c += 256) {
        int f = c >> 7, rem = c & 127;
        int pos = rem >> 1, d0 = (rem & 1) * 8;
        size_t n = (size_t)b * 20480 + (size_t)f * 4096 +
                   (vertical ? (pos * 64 + lw) : (lw * 64 + pos));
        size_t src = n * 384 + head * 16 + d0;
        *(uint4*)&qL[c * 8] = *(const uint4*)&qkv[src];
        *(uint4*)&kL[c * 8] = *(const uint4*)&qkv[src + 128];
        *(uint4*)&vL[c * 8] = *(const uint4*)&qkv[src + 256];
    }
    __syncthreads();
    int lane = tid & 63, wwv = tid >> 6;
    for (int p = wwv; p < 25; p += 4) {
        int qf = p / 5, kf = p - qf * 5;
        float acc = 0.f;
        const unsigned short* qp = &qL[qf * 1024 + lane * 16];
        const unsigned short* kp = &kL[kf * 1024 + lane * 16];
        #pragma unroll
        for (int t = 0; t < 16; ++t) acc += bf2f(qp[t]) * bf2f(kp[t]);
        for (int off = 32; off; off >>= 1) acc += __shfl_down(acc, off);
        if (lane == 0) sL[p] = acc * 0.03125f;   // 1/sqrt(1024)
    }
    __syncthreads();
    if (tid < 5) {
        float mx = -1e30f;
        for (int kf = 0; kf < 5; ++kf) mx = fmaxf(mx, sL[tid * 5 + kf]);
        float e[5], sum = 0.f;
        for (int kf = 0; kf < 5; ++kf) { e[kf] = expf(sL[tid * 5 + kf] - mx); sum += e[kf]; }
        float inv = 1.f / sum;
        for (int kf = 0; kf < 5; ++kf) sL[tid * 5 + kf] = e[kf] * inv;
    }
    __syncthreads();
    int coff = vertical ? 128 : 0;
    for (int c = tid; c < 640; c += 256) {
        int qf = c >> 7, rem = c & 127;
        int pos = rem >> 1, d0 = (rem & 1) * 8;
        float accv[8] = {};
        #pragma unroll
        for (int kf = 0; kf < 5; ++kf) {
            float w = sL[qf * 5 + kf];
            const unsigned short* vp = &vL[kf * 1024 + rem * 8];
            #pragma unroll
            for (int e = 0; e < 8; ++e) accv[e] += w * bf2f(vp[e]);
        }
        unsigned short pk[8];
        #pragma unroll
        for (int e = 0; e < 8; ++e) pk[e] = f2bf(accv[e]);
        size_t n = (size_t)b * 20480 + (size_t)qf * 4096 +
                   (vertical ? (pos * 64 + lw) : (lw * 64 + pos));
        *(uint4*)&ao[n * 256 + coff + head * 16 + d0] = *(const uint4*)pk;
    }
}

extern "C" void kernel_launch(void* const* d_in, const int* in_sizes, int n_in,
                              void* d_out, int out_size, void* d_ws, size_t ws_size,
                              hipStream_t stream) {
    (void)in_sizes; (void)n_in; (void)out_size; (void)ws_size;
    const float* x    = (const float*)d_in[0];
    const float* ln1g = (const float*)d_in[1];
    const float* ln1b = (const float*)d_in[2];
    const float* wh   = (const float*)d_in[3];
    const float* bh   = (const float*)d_in[4];
    const float* wv   = (const float*)d_in[5];
    const float* bv   = (const float*)d_in[6];
    const float* wf   = (const float*)d_in[7];
    const float* bfp  = (const float*)d_in[8];
    const float* ln2g = (const float*)d_in[9];
    const float* ln2b = (const float*)d_in[10];
    const float* w1   = (const float*)d_in[11];
    const float* b1   = (const float*)d_in[12];
    const float* w2   = (const float*)d_in[13];
    const float* b2   = (const float*)d_in[14];
    float* out = (float*)d_out;
    char* ws = (char*)d_ws;

    // workspace layout
    unsigned short* whb = (unsigned short*)(ws + 0);
    unsigned short* wvb = (unsigned short*)(ws + 98304);
    unsigned short* wfb = (unsigned short*)(ws + 196608);
    unsigned short* w1b = (unsigned short*)(ws + 327680);    // w1p frag-major, 512KB
    unsigned short* w2b = (unsigned short*)(ws + 851968);    // w2p frag-major, 512KB
    const size_t off = 1572864;
    unsigned short* tnb  = (unsigned short*)(ws + off);                    // 21.0 MB (frag-major)
    unsigned short* xt   = (unsigned short*)(ws + off + 20971520ull);      // 21.0 MB
    unsigned short* qkvh = (unsigned short*)(ws + off + 41943040ull);      // 31.5 MB
    unsigned short* qkvv = (unsigned short*)(ws + off + 73400320ull);      // 31.5 MB
    unsigned short* ao   = (unsigned short*)(ws + off + 104857600ull);     // 21.0 MB
    unsigned short* yb   = (unsigned short*)(ws + off + 125829120ull);     // 21.0 MB

    cvt_all_kernel<<<896, 256, 0, stream>>>(wh, wv, wf, w1, w2, whb, wvb, wfb, w1b, w2b);

    // fused LN1 + QKV (both halves): writes xt, qkvh, qkvv
    ln1qkv_kernel<<<640, 256, 0, stream>>>(x, ln1g, ln1b, whb, bh, wvb, bv, xt, qkvh, qkvv);

    attn_kernel<<<2048, 256, 0, stream>>>(qkvh, qkvv, ao);

    // proj + residual + LN2 (fused): yb = ao@wf^T + bf + x ; tnb = LN2(yb) [frag-major]
    gemm_t<32, 256, 4, 4><<<dim3(1, 1280), 256, 0, stream>>>(ao, 256, wfb, bfp, yb, 256, xt, nullptr,
                                                             256, ln2g, ln2b, tnb);

    // fused FFN1+FFN2: out = (yb + gelu(tn@w1p+b1)@w2p + b2) -> (B,F,C,H,W) fp32
    ffn_fused_kernel<<<640, 512, 0, stream>>>(tnb, w1b, b1, w2b, b2, yb, out);
}

// Round 6
// 416.797 us; speedup vs baseline: 1.4328x; 1.4328x over previous
//
#include <hip/hip_runtime.h>
#include <cstdint>
#include <cmath>

// Problem constants: B=2, F=5, C=256, H=64, W=64, HN=8, hd=16
// Token layout: n = (b*5+f)*4096 + h*64 + w, N = 40960 tokens, channels-last.

typedef __bf16 bf16x8 __attribute__((ext_vector_type(8)));
typedef float f32x4 __attribute__((ext_vector_type(4)));

__device__ __forceinline__ unsigned short f2bf(float f) {
    union { float f; unsigned int u; } v; v.f = f;
    unsigned int r = (v.u + 0x7fffu + ((v.u >> 16) & 1u)) >> 16;
    return (unsigned short)r;
}
__device__ __forceinline__ float bf2f(unsigned short h) {
    union { unsigned int u; float f; } v; v.u = ((unsigned int)h) << 16;
    return v.f;
}
// tanh-form GELU, fully inline
__device__ __forceinline__ float gelu_fast(float x) {
    float z2 = 2.8853900817779268f * x * (0.7978845608028654f + 0.0356774081363001f * x * x);
    float u = __builtin_amdgcn_exp2f(z2);
    return x - x * __builtin_amdgcn_rcpf(1.0f + u);
}

// async global->LDS, 16B per lane; LDS dest = wave-uniform base + lane*16
__device__ __forceinline__ void gld16(const unsigned short* g, unsigned short* l) {
    __builtin_amdgcn_global_load_lds(
        (const __attribute__((address_space(1))) void*)g,
        (__attribute__((address_space(3))) void*)l, 16, 0, 0);
}

// ---------------- weight convert: wh/wv/wf row-major bf16; w1/w2 MFMA-fragment-major ----------------
// R3 postmortem: per-lane weight-fragment loads (16-row stride-512B scatter) were the FFN
// latency killer. w1p/w2p are packed so each fragment is a CONTIGUOUS 1KB block: lane l's
// 16B at [frag*1024 + l*16]. One coalesced wave-load per fragment, pure L2 streaming.
//   w1p frag id: ((g*4 + fi)*8 + ks)  g=hid-ch/64, fi=16-row group, ks=k/32  (row=g*64+fi*16+r16, k=ks*32+kg*8)
//   w2p frag id: (cg*32 + ksg)        cg=outcol/16, ksg=k/32                (row=cg*16+r16,      k=ksg*32+kg*8)
__global__ __launch_bounds__(256) void cvt_all_kernel(
        const float* __restrict__ wh, const float* __restrict__ wv,
        const float* __restrict__ wf, const float* __restrict__ w1,
        const float* __restrict__ w2,
        unsigned short* __restrict__ whb, unsigned short* __restrict__ wvb,
        unsigned short* __restrict__ wfb, unsigned short* __restrict__ w1b,
        unsigned short* __restrict__ w2b) {
    int i = blockIdx.x * 256 + threadIdx.x;   // grid covers 229376 exactly
    if (i < 163840) {
        const float* s; unsigned short* d; int j;
        if (i < 49152)      { s = wh; d = whb; j = i; }
        else if (i < 98304) { s = wv; d = wvb; j = i - 49152; }
        else                { s = wf; d = wfb; j = i - 98304; }
        d[j] = f2bf(s[j]);
    } else if (i < 196608) {
        int t = i - 163840;                   // 32768 threads x 8 elements
        int lane = t & 63, ks = (t >> 6) & 7, fi = (t >> 9) & 3, g = t >> 11;
        int row = g * 64 + fi * 16 + (lane & 15);
        int k0 = ks * 32 + (lane >> 4) * 8;
        const float* s = w1 + (size_t)row * 256 + k0;
        unsigned short o[8];
        #pragma unroll
        for (int e = 0; e < 8; ++e) o[e] = f2bf(s[e]);
        *(uint4*)&w1b[(size_t)t * 8] = *(const uint4*)o;
    } else {
        int u = i - 196608;                   // 32768 threads x 8 elements
        int lane = u & 63, ksg = (u >> 6) & 31, cg = u >> 11;
        int row = cg * 16 + (lane & 15);
        int k0 = ksg * 32 + (lane >> 4) * 8;
        const float* s = w2 + (size_t)row * 1024 + k0;
        unsigned short o[8];
        #pragma unroll
        for (int e = 0; e < 8; ++e) o[e] = f2bf(s[e]);
        *(uint4*)&w2b[(size_t)u * 8] = *(const uint4*)o;
    }
}

// ---------------- fused LN1 + QKV(h&v): one block per (bf, h) line (64 tokens) ----------------
__global__ __launch_bounds__(256) void ln1qkv_kernel(
        const float* __restrict__ x,
        const float* __restrict__ g, const float* __restrict__ bta,
        const unsigned short* __restrict__ whb, const float* __restrict__ bh,
        const unsigned short* __restrict__ wvb, const float* __restrict__ bv,
        unsigned short* __restrict__ xt,
        unsigned short* __restrict__ qkvh, unsigned short* __restrict__ qkvv) {
    __shared__ __align__(16) unsigned short At[64 * 264];   // 33792 B, [token][ch] padded
    __shared__ __align__(16) unsigned short Bs[128 * 64];   // 16384 B, one BK=64 B-tile
    __shared__ float psum[4][64], psq[4][64], meanL[64], rstdL[64];
    __shared__ float gg[256], bb[256];

    int bx = blockIdx.x;
    int bf = bx >> 6, h = bx & 63;
    size_t base = (size_t)bf * 1048576 + (size_t)h * 64;
    int tid = threadIdx.x;
    int w = tid & 63, cg = tid >> 6;
    float s = 0.f, sq = 0.f;
    for (int k = 0; k < 64; ++k) {
        int c = cg * 64 + k;
        float v = x[base + (size_t)c * 4096 + w];
        s += v; sq += v * v;
        At[w * 264 + c] = f2bf(v);
    }
    psum[cg][w] = s; psq[cg][w] = sq;
    gg[tid] = g[tid]; bb[tid] = bta[tid];
    __syncthreads();
    if (tid < 64) {
        float ss = psum[0][tid] + psum[1][tid] + psum[2][tid] + psum[3][tid];
        float qq = psq[0][tid] + psq[1][tid] + psq[2][tid] + psq[3][tid];
        float mean = ss * (1.f / 256.f);
        float var = qq * (1.f / 256.f) - mean * mean;
        meanL[tid] = mean;
        rstdL[tid] = rsqrtf(var + 1e-5f);
    }
    __syncthreads();
    int n0g = bf * 4096 + h * 64;
    for (int t = 0; t < 8; ++t) {
        int idx = t * 256 + tid;
        int tok = idx >> 5, cc = idx & 31;
        unsigned short raw[8];
        *(uint4*)raw = *(const uint4*)&At[tok * 264 + cc * 8];
        *(uint4*)&xt[(size_t)(n0g + tok) * 256 + cc * 8] = *(const uint4*)raw;
        float mean = meanL[tok], rstd = rstdL[tok];
        unsigned short nm[8];
        #pragma unroll
        for (int e = 0; e < 8; ++e) {
            int ch = cc * 8 + e;
            nm[e] = f2bf((bf2f(raw[e]) - mean) * rstd * gg[ch] + bb[ch]);
        }
        *(uint4*)&At[tok * 264 + cc * 8] = *(const uint4*)nm;
    }
    __syncthreads();

    int lane = tid & 63, wvid = tid >> 6;
    int r16 = lane & 15, kg = lane >> 4;
    int srow = wvid * 8 + (lane >> 3);
    int segg = (lane & 7) ^ (lane >> 3);
    unsigned short* lB = Bs + wvid * 512;
    for (int t = 0; t < 6; ++t) {
        const unsigned short* Wt; const float* bias; unsigned short* dst; int ot, aoff;
        if (t < 3) { Wt = whb + t * 16384;       bias = bh + t * 128;       dst = qkvh; ot = t * 128;       aoff = 0; }
        else       { Wt = wvb + (t - 3) * 16384; bias = bv + (t - 3) * 128; dst = qkvv; ot = (t - 3) * 128; aoff = 128; }
        f32x4 acc[4][2] = {};
        for (int kk = 0; kk < 2; ++kk) {
            const unsigned short* pB = Wt + (size_t)srow * 128 + kk * 64 + segg * 8;
            #pragma unroll
            for (int i = 0; i < 4; ++i)
                gld16(pB + (size_t)i * 32 * 128, lB + i * 2048);
            __syncthreads();
            #pragma unroll
            for (int tt = 0; tt < 2; ++tt) {
                int ka = aoff + kk * 64 + (tt * 4 + kg) * 8;
                int ss = ((tt * 4 + kg) ^ (r16 & 7)) * 8;
                bf16x8 af[4], bfr[2];
                #pragma unroll
                for (int i = 0; i < 4; ++i)
                    af[i] = *(const bf16x8*)&At[(i * 16 + r16) * 264 + ka];
                #pragma unroll
                for (int j = 0; j < 2; ++j)
                    bfr[j] = *(const bf16x8*)&Bs[(wvid * 32 + j * 16 + r16) * 64 + ss];
                #pragma unroll
                for (int i = 0; i < 4; ++i)
                    #pragma unroll
                    for (int j = 0; j < 2; ++j)
                        acc[i][j] = __builtin_amdgcn_mfma_f32_16x16x32_bf16(af[i], bfr[j], acc[i][j], 0, 0, 0);
            }
            __syncthreads();
        }
        float biasv[2];
        #pragma unroll
        for (int j = 0; j < 2; ++j) biasv[j] = bias[wvid * 32 + j * 16 + r16];
        #pragma unroll
        for (int i = 0; i < 4; ++i)
            #pragma unroll
            for (int j = 0; j < 2; ++j)
                #pragma unroll
                for (int r = 0; r < 4; ++r) {
                    int m = i * 16 + kg * 4 + r;
                    int nc = ot + wvid * 32 + j * 16 + r16;
                    dst[(size_t)(n0g + m) * 384 + nc] = f2bf(acc[i][j][r] + biasv[j]);
                }
    }
}

// ---------------- templated MFMA GEMM (only MODE 4 = proj+LN2 instantiated) ----------------
// MODE 4 writes C2 (tn) in FRAGMENT-MAJOR layout (R4): tnb[((line*32 + jj*8 + ks)*64
// + kgc*16 + r16r)*8 + e] holds tn[line*64 + jj*16 + r16r][ks*32 + kgc*8 + e], so the FFN
// kernel's phase-1 B-fragments are lane-linear 1KB wave-loads (no LDS staging needed).
// NOTE: every acc[] subscript must be compile-time constant (dynamic indexing
// spills the whole accumulator array to scratch -- R8 postmortem: 1.36 GB scratch traffic).
template<int BM, int BN, int MODE, int MINW>
__global__ __launch_bounds__(256, MINW) void gemm_t(
        const unsigned short* __restrict__ A, int lda,
        const unsigned short* __restrict__ B,
        const float* __restrict__ bias,
        unsigned short* __restrict__ C, int ldc,
        const unsigned short* __restrict__ res,
        float* __restrict__ outT,
        int K,
        const float* __restrict__ g2, const float* __restrict__ b2,
        unsigned short* __restrict__ C2) {
    constexpr int WCOL = BN / 4;        // cols per wave
    constexpr int MR = BM / 16;         // 16-row fragments per wave
    constexpr int NR = WCOL / 16;       // 16-col fragments per wave
    constexpr int AG = BM / 32;         // A gld16 per wave per K-step
    constexpr int BG = BN / 32;         // B gld16 per wave per K-step
    __shared__ __align__(16) unsigned char smem[(BM + BN) * 128];
    unsigned short* As = (unsigned short*)smem;
    unsigned short* Bs = (unsigned short*)(smem + BM * 128);

    int tid = threadIdx.x;
    int lane = tid & 63, wvid = tid >> 6;
    int r16 = lane & 15, kg = lane >> 4;

    // XCD-aware remap (total blocks divisible by 8 in all configs)
    int nx = gridDim.x;
    int L = blockIdx.y * nx + blockIdx.x;
    int T = nx * gridDim.y;
    int newL = (T & 7) ? L : ((L & 7) * (T >> 3) + (L >> 3));
    int nt = newL % nx, mt = newL / nx;
    int m0 = mt * BM, n0 = nt * BN;

    int srow = wvid * 8 + (lane >> 3);
    int segg = (lane & 7) ^ (lane >> 3);
    const unsigned short* pA = A + (size_t)(m0 + srow) * lda + segg * 8;
    const unsigned short* pB = B + (size_t)(n0 + srow) * K + segg * 8;
    unsigned short* lA = As + wvid * 512;
    unsigned short* lB = Bs + wvid * 512;

    f32x4 acc[MR][NR] = {};
    for (int k0 = 0; k0 < K; k0 += 64) {
        #pragma unroll
        for (int i = 0; i < AG; ++i)
            gld16(pA + (size_t)i * 32 * lda, lA + i * 2048);
        #pragma unroll
        for (int i = 0; i < BG; ++i)
            gld16(pB + (size_t)i * 32 * K, lB + i * 2048);
        pA += 64; pB += 64;
        __syncthreads();
        #pragma unroll
        for (int t = 0; t < 2; ++t) {
            bf16x8 af[MR], bfr[NR];
            int ss = ((t * 4 + kg) ^ (r16 & 7)) * 8;
            #pragma unroll
            for (int i = 0; i < MR; ++i)
                af[i] = *(const bf16x8*)&As[(i * 16 + r16) * 64 + ss];
            #pragma unroll
            for (int j = 0; j < NR; ++j)
                bfr[j] = *(const bf16x8*)&Bs[(wvid * WCOL + j * 16 + r16) * 64 + ss];
            #pragma unroll
            for (int i = 0; i < MR; ++i)
                #pragma unroll
                for (int j = 0; j < NR; ++j)
                    acc[i][j] = __builtin_amdgcn_mfma_f32_16x16x32_bf16(af[i], bfr[j], acc[i][j], 0, 0, 0);
        }
        __syncthreads();
    }

    if constexpr (MODE == 4) {
        // BM=32, BN=256: y = acc + bias + res -> C (yb); row LN over 256 cols -> C2 (tn, frag-major)
        float* ssum = (float*)smem;             // [BM][4]
        float* ssq  = ssum + BM * 4;
        float biasv[NR];
        #pragma unroll
        for (int j = 0; j < NR; ++j) biasv[j] = bias[n0 + wvid * WCOL + j * 16 + r16];
        const unsigned short* resp = res + (size_t)m0 * 256 + wvid * WCOL;
        #pragma unroll
        for (int i = 0; i < MR; ++i)
            #pragma unroll
            for (int r = 0; r < 4; ++r) {
                int row = i * 16 + kg * 4 + r;
                #pragma unroll
                for (int j = 0; j < NR; ++j) {
                    float v = acc[i][j][r] + biasv[j] + bf2f(resp[(size_t)row * 256 + j * 16 + r16]);
                    acc[i][j][r] = v;
                    C[(size_t)(m0 + row) * 256 + wvid * WCOL + j * 16 + r16] = f2bf(v);
                }
            }
        #pragma unroll
        for (int i = 0; i < MR; ++i)
            #pragma unroll
            for (int r = 0; r < 4; ++r) {
                float s = 0.f, sq = 0.f;
                #pragma unroll
                for (int j = 0; j < NR; ++j) { float v = acc[i][j][r]; s += v; sq += v * v; }
                s += __shfl_xor(s, 1); sq += __shfl_xor(sq, 1);
                s += __shfl_xor(s, 2); sq += __shfl_xor(sq, 2);
                s += __shfl_xor(s, 4); sq += __shfl_xor(sq, 4);
                s += __shfl_xor(s, 8); sq += __shfl_xor(sq, 8);
                if (r16 == 0) {
                    int mr = i * 16 + kg * 4 + r;
                    ssum[mr * 4 + wvid] = s;
                    ssq[mr * 4 + wvid] = sq;
                }
            }
        __syncthreads();
        float g2v[NR], b2v[NR];
        #pragma unroll
        for (int j = 0; j < NR; ++j) {
            g2v[j] = g2[wvid * WCOL + j * 16 + r16];
            b2v[j] = b2[wvid * WCOL + j * 16 + r16];
        }
        #pragma unroll
        for (int i = 0; i < MR; ++i)
            #pragma unroll
            for (int r = 0; r < 4; ++r) {
                int mr = i * 16 + kg * 4 + r;
                float sum = ssum[mr * 4] + ssum[mr * 4 + 1] + ssum[mr * 4 + 2] + ssum[mr * 4 + 3];
                float sq  = ssq[mr * 4] + ssq[mr * 4 + 1] + ssq[mr * 4 + 2] + ssq[mr * 4 + 3];
                float mean = sum * (1.f / 256.f);
                float var = sq * (1.f / 256.f) - mean * mean;
                float rstd = rsqrtf(var + 1e-5f);
                int row = m0 + mr;
                size_t lbase = (((size_t)(row >> 6)) * 32 + (size_t)(((row & 63) >> 4) * 8));
                #pragma unroll
                for (int j = 0; j < NR; ++j) {
                    float tv = (acc[i][j][r] - mean) * rstd * g2v[j] + b2v[j];
                    int col = wvid * WCOL + j * 16 + r16;
                    // frag-major store: frag (jj, ks), lane kgc*16+r16r, elem e
                    C2[((lbase + (col >> 5)) * 64 + ((col >> 3) & 3) * 16 + (row & 15)) * 8 + (col & 7)] = f2bf(tv);
                }
            }
    }
}

// ---------------- fused FFN v3b: no tn staging (frag-major tnb), hid-only LDS ----------------
// R5 postmortem: __launch_bounds__(512,8) capped VGPR at 64 (512 regs/lane-slot / 8 waves);
// live set ~100 -> allocator spilled accumulators to scratch (VGPR_Count 32, 1.1GB HBM
// scratch traffic, 436us). NEVER cap registers below the live set. (512,4) caps at 128.
// Structure unchanged from v3: tnb frag-major (lane-linear 1KB B-frag loads from L1/L2),
// no tnL staging, LDS = hidL 32KB only, 1 barrier pair per chunk.
__global__ __launch_bounds__(512, 4) void ffn_fused_kernel(
        const unsigned short* __restrict__ tnb,   // frag-major per line: [line][32 frags][64 lanes][8]
        const unsigned short* __restrict__ w1p,   // frag-major, see cvt
        const float* __restrict__ b1,
        const unsigned short* __restrict__ w2p,   // frag-major, see cvt
        const float* __restrict__ b2,
        const unsigned short* __restrict__ yb,    // residual [40960][256] bf16
        float* __restrict__ outT) {               // (B,F,C,H,W) fp32
    __shared__ __align__(16) unsigned short hidL[64 * 256];  // 32KB, frag-major [ks*4+i][lane][8]

    int tid = threadIdx.x;
    int lane = tid & 63, wv = tid >> 6;           // 8 waves
    int r16 = lane & 15, kg = lane >> 4;

    // XCD-aware remap: 640 blocks, 80 per XCD contiguous
    int L = blockIdx.x;
    int blk = (L & 7) * 80 + (L >> 3);
    int m0 = blk * 64;                            // one (bf,h) line of 64 tokens

    const unsigned short* tp = tnb + (size_t)blk * 16384;   // this line's 32 tn fragments

    f32x4 acc2[4][2] = {};                        // out tile: 64 tok x 32 cols (cols wv*32..)

    for (int c = 0; c < 4; ++c) {                 // hid chunks of 256 channels
        // ---- phase 1: hid chunk ch = c*256 + wv*32 + i'*16 + (kg*4+r), tok = j*16+r16 ----
        f32x4 acc[2][4] = {};
        {
            int g = c * 4 + (wv >> 1);
            const unsigned short* ap = w1p + ((size_t)((g * 4 + (wv & 1) * 2) * 8) * 64 + lane) * 8;
            #pragma unroll
            for (int ks = 0; ks < 8; ++ks) {
                bf16x8 a0 = *(const bf16x8*)(ap + (size_t)ks * 512);
                bf16x8 a1 = *(const bf16x8*)(ap + (size_t)4096 + ks * 512);
                bf16x8 b[4];
                #pragma unroll
                for (int j = 0; j < 4; ++j)
                    b[j] = *(const bf16x8*)(tp + ((j * 8 + ks) * 64 + lane) * 8);
                #pragma unroll
                for (int j = 0; j < 4; ++j) {
                    acc[0][j] = __builtin_amdgcn_mfma_f32_16x16x32_bf16(a0, b[j], acc[0][j], 0, 0, 0);
                    acc[1][j] = __builtin_amdgcn_mfma_f32_16x16x32_bf16(a1, b[j], acc[1][j], 0, 0, 0);
                }
            }
        }
        // bias + GELU + pack 4 consecutive ch -> 8B frag-major write (4-way = write floor)
        #pragma unroll
        for (int ip = 0; ip < 2; ++ip) {
            int ch0 = c * 256 + wv * 32 + ip * 16 + kg * 4;
            float bb0 = b1[ch0], bb1 = b1[ch0 + 1], bb2 = b1[ch0 + 2], bb3 = b1[ch0 + 3];
            #pragma unroll
            for (int j = 0; j < 4; ++j) {
                float g0 = gelu_fast(acc[ip][j][0] + bb0);
                float g1 = gelu_fast(acc[ip][j][1] + bb1);
                float g2 = gelu_fast(acc[ip][j][2] + bb2);
                float g3 = gelu_fast(acc[ip][j][3] + bb3);
                uint2 pk;
                pk.x = (unsigned int)f2bf(g0) | ((unsigned int)f2bf(g1) << 16);
                pk.y = (unsigned int)f2bf(g2) | ((unsigned int)f2bf(g3) << 16);
                unsigned int hb = (((unsigned int)(wv * 4 + j) * 64 +
                                    (ip * 2 + (kg >> 1)) * 16 + r16) << 4) + ((kg & 1) << 3);
                *(uint2*)((char*)hidL + hb) = pk;
            }
        }
        __syncthreads();
        // ---- phase 2: acc2 += hid_chunk @ w2^T (A from LDS linear, B from w2p L2 stream) ----
        {
            const unsigned short* bp0 = w2p + ((size_t)((wv * 2) * 32 + c * 8) * 64 + lane) * 8;
            const unsigned short* bp1 = w2p + ((size_t)((wv * 2 + 1) * 32 + c * 8) * 64 + lane) * 8;
            #pragma unroll
            for (int ks = 0; ks < 8; ++ks) {
                bf16x8 a[4];
                #pragma unroll
                for (int i = 0; i < 4; ++i)
                    a[i] = *(const bf16x8*)&hidL[((ks * 4 + i) * 64 + lane) * 8];
                bf16x8 b0 = *(const bf16x8*)(bp0 + (size_t)ks * 512);
                bf16x8 b1v = *(const bf16x8*)(bp1 + (size_t)ks * 512);
                #pragma unroll
                for (int i = 0; i < 4; ++i) {
                    acc2[i][0] = __builtin_amdgcn_mfma_f32_16x16x32_bf16(a[i], b0, acc2[i][0], 0, 0, 0);
                    acc2[i][1] = __builtin_amdgcn_mfma_f32_16x16x32_bf16(a[i], b1v, acc2[i][1], 0, 0, 0);
                }
            }
        }
        __syncthreads();
    }

    // ---- epilogue: + b2 + yb residual, fp32 transposed store (hidL dead -> reuse as fl) ----
    float* fl = (float*)hidL;                     // [64 tokens][64 ch] fp32, XOR col swizzle (16KB)
    int bfi = m0 >> 12;
    int hh = (m0 >> 6) & 63;
    #pragma unroll
    for (int p = 0; p < 4; ++p) {                 // channel groups of 64 = waves {2p, 2p+1}
        __syncthreads();
        if ((wv >> 1) == p) {
            #pragma unroll
            for (int i = 0; i < 4; ++i)
                #pragma unroll
                for (int j = 0; j < 2; ++j)
                    #pragma unroll
                    for (int r = 0; r < 4; ++r) {
                        int ml = i * 16 + kg * 4 + r;            // token within line
                        int nl = (wv & 1) * 32 + j * 16 + r16;   // channel within group
                        int n = p * 64 + nl;
                        float v = acc2[i][j][r] + b2[n] + bf2f(yb[(size_t)(m0 + ml) * 256 + n]);
                        fl[ml * 64 + (nl ^ ml)] = v;
                    }
        }
        __syncthreads();
        for (int r = wv; r < 64; r += 8) {
            outT[(size_t)bfi * 1048576 + (size_t)(p * 64 + r) * 4096 +
                 (size_t)hh * 64 + lane] = fl[lane * 64 + (r ^ lane)];
        }
    }
}

// ---------------- attention (both directions, one launch): per (dir, b, head, line) ----------------
__global__ __launch_bounds__(256) void attn_kernel(const unsigned short* __restrict__ qkvH,
                                                   const unsigned short* __restrict__ qkvV,
                                                   unsigned short* __restrict__ ao) {
    __shared__ unsigned short qL[5 * 1024], kL[5 * 1024], vL[5 * 1024];
    __shared__ float sL[25];
    int g = blockIdx.x;
    int vertical = g >> 10;
    const unsigned short* qkv = vertical ? qkvV : qkvH;
    int lw = g & 63;
    int head = (g >> 6) & 7;
    int b = (g >> 9) & 1;
    int tid = threadIdx.x;
    for (int c = tid; c < 640; c += 256) {
        int f = c >> 7, rem = c & 127;
        int pos = rem >> 1, d0 = (rem & 1) * 8;
        size_t n = (size_t)b * 20480 + (size_t)f * 4096 +
                   (vertical ? (pos * 64 + lw) : (lw * 64 + pos));
        size_t src = n * 384 + head * 16 + d0;
        *(uint4*)&qL[c * 8] = *(const uint4*)&qkv[src];
        *(uint4*)&kL[c * 8] = *(const uint4*)&qkv[src + 128];
        *(uint4*)&vL[c * 8] = *(const uint4*)&qkv[src + 256];
    }
    __syncthreads();
    int lane = tid & 63, wwv = tid >> 6;
    for (int p = wwv; p < 25; p += 4) {
        int qf = p / 5, kf = p - qf * 5;
        float acc = 0.f;
        const unsigned short* qp = &qL[qf * 1024 + lane * 16];
        const unsigned short* kp = &kL[kf * 1024 + lane * 16];
        #pragma unroll
        for (int t = 0; t < 16; ++t) acc += bf2f(qp[t]) * bf2f(kp[t]);
        for (int off = 32; off; off >>= 1) acc += __shfl_down(acc, off);
        if (lane == 0) sL[p] = acc * 0.03125f;   // 1/sqrt(1024)
    }
    __syncthreads();
    if (tid < 5) {
        float mx = -1e30f;
        for (int kf = 0; kf < 5; ++kf) mx = fmaxf(mx, sL[tid * 5 + kf]);
        float e[5], sum = 0.f;
        for (int kf = 0; kf < 5; ++kf) { e[kf] = expf(sL[tid * 5 + kf] - mx); sum += e[kf]; }
        float inv = 1.f / sum;
        for (int kf = 0; kf < 5; ++kf) sL[tid * 5 + kf] = e[kf] * inv;
    }
    __syncthreads();
    int coff = vertical ? 128 : 0;
    for (int c = tid; c < 640; c += 256) {
        int qf = c >> 7, rem = c & 127;
        int pos = rem >> 1, d0 = (rem & 1) * 8;
        float accv[8] = {};
        #pragma unroll
        for (int kf = 0; kf < 5; ++kf) {
            float w = sL[qf * 5 + kf];
            const unsigned short* vp = &vL[kf * 1024 + rem * 8];
            #pragma unroll
            for (int e = 0; e < 8; ++e) accv[e] += w * bf2f(vp[e]);
        }
        unsigned short pk[8];
        #pragma unroll
        for (int e = 0; e < 8; ++e) pk[e] = f2bf(accv[e]);
        size_t n = (size_t)b * 20480 + (size_t)qf * 4096 +
                   (vertical ? (pos * 64 + lw) : (lw * 64 + pos));
        *(uint4*)&ao[n * 256 + coff + head * 16 + d0] = *(const uint4*)pk;
    }
}

extern "C" void kernel_launch(void* const* d_in, const int* in_sizes, int n_in,
                              void* d_out, int out_size, void* d_ws, size_t ws_size,
                              hipStream_t stream) {
    (void)in_sizes; (void)n_in; (void)out_size; (void)ws_size;
    const float* x    = (const float*)d_in[0];
    const float* ln1g = (const float*)d_in[1];
    const float* ln1b = (const float*)d_in[2];
    const float* wh   = (const float*)d_in[3];
    const float* bh   = (const float*)d_in[4];
    const float* wv   = (const float*)d_in[5];
    const float* bv   = (const float*)d_in[6];
    const float* wf   = (const float*)d_in[7];
    const float* bfp  = (const float*)d_in[8];
    const float* ln2g = (const float*)d_in[9];
    const float* ln2b = (const float*)d_in[10];
    const float* w1   = (const float*)d_in[11];
    const float* b1   = (const float*)d_in[12];
    const float* w2   = (const float*)d_in[13];
    const float* b2   = (const float*)d_in[14];
    float* out = (float*)d_out;
    char* ws = (char*)d_ws;

    // workspace layout
    unsigned short* whb = (unsigned short*)(ws + 0);
    unsigned short* wvb = (unsigned short*)(ws + 98304);
    unsigned short* wfb = (unsigned short*)(ws + 196608);
    unsigned short* w1b = (unsigned short*)(ws + 327680);    // w1p frag-major, 512KB
    unsigned short* w2b = (unsigned short*)(ws + 851968);    // w2p frag-major, 512KB
    const size_t off = 1572864;
    unsigned short* tnb  = (unsigned short*)(ws + off);                    // 21.0 MB (frag-major)
    unsigned short* xt   = (unsigned short*)(ws + off + 20971520ull);      // 21.0 MB
    unsigned short* qkvh = (unsigned short*)(ws + off + 41943040ull);      // 31.5 MB
    unsigned short* qkvv = (unsigned short*)(ws + off + 73400320ull);      // 31.5 MB
    unsigned short* ao   = (unsigned short*)(ws + off + 104857600ull);     // 21.0 MB
    unsigned short* yb   = (unsigned short*)(ws + off + 125829120ull);     // 21.0 MB

    cvt_all_kernel<<<896, 256, 0, stream>>>(wh, wv, wf, w1, w2, whb, wvb, wfb, w1b, w2b);

    // fused LN1 + QKV (both halves): writes xt, qkvh, qkvv
    ln1qkv_kernel<<<640, 256, 0, stream>>>(x, ln1g, ln1b, whb, bh, wvb, bv, xt, qkvh, qkvv);

    attn_kernel<<<2048, 256, 0, stream>>>(qkvh, qkvv, ao);

    // proj + residual + LN2 (fused): yb = ao@wf^T + bf + x ; tnb = LN2(yb) [frag-major]
    gemm_t<32, 256, 4, 4><<<dim3(1, 1280), 256, 0, stream>>>(ao, 256, wfb, bfp, yb, 256, xt, nullptr,
                                                             256, ln2g, ln2b, tnb);

    // fused FFN1+FFN2: out = (yb + gelu(tn@w1p+b1)@w2p + b2) -> (B,F,C,H,W) fp32
    ffn_fused_kernel<<<640, 512, 0, stream>>>(tnb, w1b, b1, w2b, b2, yb, out);
}

// Round 7
// 302.659 us; speedup vs baseline: 1.9731x; 1.3771x over previous
//
#include <hip/hip_runtime.h>
#include <cstdint>
#include <cmath>

// Problem constants: B=2, F=5, C=256, H=64, W=64, HN=8, hd=16
// Token layout: n = (b*5+f)*4096 + h*64 + w, N = 40960 tokens, channels-last.

typedef __bf16 bf16x8 __attribute__((ext_vector_type(8)));
typedef float f32x4 __attribute__((ext_vector_type(4)));

__device__ __forceinline__ unsigned short f2bf(float f) {
    union { float f; unsigned int u; } v; v.f = f;
    unsigned int r = (v.u + 0x7fffu + ((v.u >> 16) & 1u)) >> 16;
    return (unsigned short)r;
}
__device__ __forceinline__ float bf2f(unsigned short h) {
    union { unsigned int u; float f; } v; v.u = ((unsigned int)h) << 16;
    return v.f;
}
// tanh-form GELU, fully inline
__device__ __forceinline__ float gelu_fast(float x) {
    float z2 = 2.8853900817779268f * x * (0.7978845608028654f + 0.0356774081363001f * x * x);
    float u = __builtin_amdgcn_exp2f(z2);
    return x - x * __builtin_amdgcn_rcpf(1.0f + u);
}

// async global->LDS, 16B per lane; LDS dest = wave-uniform base + lane*16
__device__ __forceinline__ void gld16(const unsigned short* g, unsigned short* l) {
    __builtin_amdgcn_global_load_lds(
        (const __attribute__((address_space(1))) void*)g,
        (__attribute__((address_space(3))) void*)l, 16, 0, 0);
}

// ---------------- weight convert: wh/wv/wf row-major bf16; w1/w2 MFMA-fragment-major ----------------
// R3 postmortem: per-lane weight-fragment loads (16-row stride-512B scatter) were the FFN
// latency killer. w1p/w2p are packed so each fragment is a CONTIGUOUS 1KB block: lane l's
// 16B at [frag*1024 + l*16]. One coalesced wave-load per fragment, pure L2 streaming.
//   w1p frag id: ((g*4 + fi)*8 + ks)  g=hid-ch/64, fi=16-row group, ks=k/32  (row=g*64+fi*16+r16, k=ks*32+kg*8)
//   w2p frag id: (cg*32 + ksg)        cg=outcol/16, ksg=k/32                (row=cg*16+r16,      k=ksg*32+kg*8)
__global__ __launch_bounds__(256) void cvt_all_kernel(
        const float* __restrict__ wh, const float* __restrict__ wv,
        const float* __restrict__ wf, const float* __restrict__ w1,
        const float* __restrict__ w2,
        unsigned short* __restrict__ whb, unsigned short* __restrict__ wvb,
        unsigned short* __restrict__ wfb, unsigned short* __restrict__ w1b,
        unsigned short* __restrict__ w2b) {
    int i = blockIdx.x * 256 + threadIdx.x;   // grid covers 229376 exactly
    if (i < 163840) {
        const float* s; unsigned short* d; int j;
        if (i < 49152)      { s = wh; d = whb; j = i; }
        else if (i < 98304) { s = wv; d = wvb; j = i - 49152; }
        else                { s = wf; d = wfb; j = i - 98304; }
        d[j] = f2bf(s[j]);
    } else if (i < 196608) {
        int t = i - 163840;                   // 32768 threads x 8 elements
        int lane = t & 63, ks = (t >> 6) & 7, fi = (t >> 9) & 3, g = t >> 11;
        int row = g * 64 + fi * 16 + (lane & 15);
        int k0 = ks * 32 + (lane >> 4) * 8;
        const float* s = w1 + (size_t)row * 256 + k0;
        unsigned short o[8];
        #pragma unroll
        for (int e = 0; e < 8; ++e) o[e] = f2bf(s[e]);
        *(uint4*)&w1b[(size_t)t * 8] = *(const uint4*)o;
    } else {
        int u = i - 196608;                   // 32768 threads x 8 elements
        int lane = u & 63, ksg = (u >> 6) & 31, cg = u >> 11;
        int row = cg * 16 + (lane & 15);
        int k0 = ksg * 32 + (lane >> 4) * 8;
        const float* s = w2 + (size_t)row * 1024 + k0;
        unsigned short o[8];
        #pragma unroll
        for (int e = 0; e < 8; ++e) o[e] = f2bf(s[e]);
        *(uint4*)&w2b[(size_t)u * 8] = *(const uint4*)o;
    }
}

// ---------------- fused LN1 + QKV(h&v): one block per (bf, h) line (64 tokens) ----------------
__global__ __launch_bounds__(256) void ln1qkv_kernel(
        const float* __restrict__ x,
        const float* __restrict__ g, const float* __restrict__ bta,
        const unsigned short* __restrict__ whb, const float* __restrict__ bh,
        const unsigned short* __restrict__ wvb, const float* __restrict__ bv,
        unsigned short* __restrict__ xt,
        unsigned short* __restrict__ qkvh, unsigned short* __restrict__ qkvv) {
    __shared__ __align__(16) unsigned short At[64 * 264];   // 33792 B, [token][ch] padded
    __shared__ __align__(16) unsigned short Bs[128 * 64];   // 16384 B, one BK=64 B-tile
    __shared__ float psum[4][64], psq[4][64], meanL[64], rstdL[64];
    __shared__ float gg[256], bb[256];

    int bx = blockIdx.x;
    int bf = bx >> 6, h = bx & 63;
    size_t base = (size_t)bf * 1048576 + (size_t)h * 64;
    int tid = threadIdx.x;
    int w = tid & 63, cg = tid >> 6;
    float s = 0.f, sq = 0.f;
    for (int k = 0; k < 64; ++k) {
        int c = cg * 64 + k;
        float v = x[base + (size_t)c * 4096 + w];
        s += v; sq += v * v;
        At[w * 264 + c] = f2bf(v);
    }
    psum[cg][w] = s; psq[cg][w] = sq;
    gg[tid] = g[tid]; bb[tid] = bta[tid];
    __syncthreads();
    if (tid < 64) {
        float ss = psum[0][tid] + psum[1][tid] + psum[2][tid] + psum[3][tid];
        float qq = psq[0][tid] + psq[1][tid] + psq[2][tid] + psq[3][tid];
        float mean = ss * (1.f / 256.f);
        float var = qq * (1.f / 256.f) - mean * mean;
        meanL[tid] = mean;
        rstdL[tid] = rsqrtf(var + 1e-5f);
    }
    __syncthreads();
    int n0g = bf * 4096 + h * 64;
    for (int t = 0; t < 8; ++t) {
        int idx = t * 256 + tid;
        int tok = idx >> 5, cc = idx & 31;
        unsigned short raw[8];
        *(uint4*)raw = *(const uint4*)&At[tok * 264 + cc * 8];
        *(uint4*)&xt[(size_t)(n0g + tok) * 256 + cc * 8] = *(const uint4*)raw;
        float mean = meanL[tok], rstd = rstdL[tok];
        unsigned short nm[8];
        #pragma unroll
        for (int e = 0; e < 8; ++e) {
            int ch = cc * 8 + e;
            nm[e] = f2bf((bf2f(raw[e]) - mean) * rstd * gg[ch] + bb[ch]);
        }
        *(uint4*)&At[tok * 264 + cc * 8] = *(const uint4*)nm;
    }
    __syncthreads();

    int lane = tid & 63, wvid = tid >> 6;
    int r16 = lane & 15, kg = lane >> 4;
    int srow = wvid * 8 + (lane >> 3);
    int segg = (lane & 7) ^ (lane >> 3);
    unsigned short* lB = Bs + wvid * 512;
    for (int t = 0; t < 6; ++t) {
        const unsigned short* Wt; const float* bias; unsigned short* dst; int ot, aoff;
        if (t < 3) { Wt = whb + t * 16384;       bias = bh + t * 128;       dst = qkvh; ot = t * 128;       aoff = 0; }
        else       { Wt = wvb + (t - 3) * 16384; bias = bv + (t - 3) * 128; dst = qkvv; ot = (t - 3) * 128; aoff = 128; }
        f32x4 acc[4][2] = {};
        for (int kk = 0; kk < 2; ++kk) {
            const unsigned short* pB = Wt + (size_t)srow * 128 + kk * 64 + segg * 8;
            #pragma unroll
            for (int i = 0; i < 4; ++i)
                gld16(pB + (size_t)i * 32 * 128, lB + i * 2048);
            __syncthreads();
            #pragma unroll
            for (int tt = 0; tt < 2; ++tt) {
                int ka = aoff + kk * 64 + (tt * 4 + kg) * 8;
                int ss = ((tt * 4 + kg) ^ (r16 & 7)) * 8;
                bf16x8 af[4], bfr[2];
                #pragma unroll
                for (int i = 0; i < 4; ++i)
                    af[i] = *(const bf16x8*)&At[(i * 16 + r16) * 264 + ka];
                #pragma unroll
                for (int j = 0; j < 2; ++j)
                    bfr[j] = *(const bf16x8*)&Bs[(wvid * 32 + j * 16 + r16) * 64 + ss];
                #pragma unroll
                for (int i = 0; i < 4; ++i)
                    #pragma unroll
                    for (int j = 0; j < 2; ++j)
                        acc[i][j] = __builtin_amdgcn_mfma_f32_16x16x32_bf16(af[i], bfr[j], acc[i][j], 0, 0, 0);
            }
            __syncthreads();
        }
        float biasv[2];
        #pragma unroll
        for (int j = 0; j < 2; ++j) biasv[j] = bias[wvid * 32 + j * 16 + r16];
        #pragma unroll
        for (int i = 0; i < 4; ++i)
            #pragma unroll
            for (int j = 0; j < 2; ++j)
                #pragma unroll
                for (int r = 0; r < 4; ++r) {
                    int m = i * 16 + kg * 4 + r;
                    int nc = ot + wvid * 32 + j * 16 + r16;
                    dst[(size_t)(n0g + m) * 384 + nc] = f2bf(acc[i][j][r] + biasv[j]);
                }
    }
}

// ---------------- templated MFMA GEMM (only MODE 4 = proj+LN2 instantiated) ----------------
// MODE 4 writes C2 (tn) in FRAGMENT-MAJOR layout (R4): tnb[((line*32 + jj*8 + ks)*64
// + kgc*16 + r16r)*8 + e] holds tn[line*64 + jj*16 + r16r][ks*32 + kgc*8 + e], so the FFN
// kernel's phase-1 B-fragments are lane-linear 1KB wave-loads (no LDS staging needed).
// NOTE: every acc[] subscript must be compile-time constant (dynamic indexing
// spills the whole accumulator array to scratch -- R8 postmortem: 1.36 GB scratch traffic).
template<int BM, int BN, int MODE, int MINW>
__global__ __launch_bounds__(256, MINW) void gemm_t(
        const unsigned short* __restrict__ A, int lda,
        const unsigned short* __restrict__ B,
        const float* __restrict__ bias,
        unsigned short* __restrict__ C, int ldc,
        const unsigned short* __restrict__ res,
        float* __restrict__ outT,
        int K,
        const float* __restrict__ g2, const float* __restrict__ b2,
        unsigned short* __restrict__ C2) {
    constexpr int WCOL = BN / 4;        // cols per wave
    constexpr int MR = BM / 16;         // 16-row fragments per wave
    constexpr int NR = WCOL / 16;       // 16-col fragments per wave
    constexpr int AG = BM / 32;         // A gld16 per wave per K-step
    constexpr int BG = BN / 32;         // B gld16 per wave per K-step
    __shared__ __align__(16) unsigned char smem[(BM + BN) * 128];
    unsigned short* As = (unsigned short*)smem;
    unsigned short* Bs = (unsigned short*)(smem + BM * 128);

    int tid = threadIdx.x;
    int lane = tid & 63, wvid = tid >> 6;
    int r16 = lane & 15, kg = lane >> 4;

    // XCD-aware remap (total blocks divisible by 8 in all configs)
    int nx = gridDim.x;
    int L = blockIdx.y * nx + blockIdx.x;
    int T = nx * gridDim.y;
    int newL = (T & 7) ? L : ((L & 7) * (T >> 3) + (L >> 3));
    int nt = newL % nx, mt = newL / nx;
    int m0 = mt * BM, n0 = nt * BN;

    int srow = wvid * 8 + (lane >> 3);
    int segg = (lane & 7) ^ (lane >> 3);
    const unsigned short* pA = A + (size_t)(m0 + srow) * lda + segg * 8;
    const unsigned short* pB = B + (size_t)(n0 + srow) * K + segg * 8;
    unsigned short* lA = As + wvid * 512;
    unsigned short* lB = Bs + wvid * 512;

    f32x4 acc[MR][NR] = {};
    for (int k0 = 0; k0 < K; k0 += 64) {
        #pragma unroll
        for (int i = 0; i < AG; ++i)
            gld16(pA + (size_t)i * 32 * lda, lA + i * 2048);
        #pragma unroll
        for (int i = 0; i < BG; ++i)
            gld16(pB + (size_t)i * 32 * K, lB + i * 2048);
        pA += 64; pB += 64;
        __syncthreads();
        #pragma unroll
        for (int t = 0; t < 2; ++t) {
            bf16x8 af[MR], bfr[NR];
            int ss = ((t * 4 + kg) ^ (r16 & 7)) * 8;
            #pragma unroll
            for (int i = 0; i < MR; ++i)
                af[i] = *(const bf16x8*)&As[(i * 16 + r16) * 64 + ss];
            #pragma unroll
            for (int j = 0; j < NR; ++j)
                bfr[j] = *(const bf16x8*)&Bs[(wvid * WCOL + j * 16 + r16) * 64 + ss];
            #pragma unroll
            for (int i = 0; i < MR; ++i)
                #pragma unroll
                for (int j = 0; j < NR; ++j)
                    acc[i][j] = __builtin_amdgcn_mfma_f32_16x16x32_bf16(af[i], bfr[j], acc[i][j], 0, 0, 0);
        }
        __syncthreads();
    }

    if constexpr (MODE == 4) {
        // BM=32, BN=256: y = acc + bias + res -> C (yb); row LN over 256 cols -> C2 (tn, frag-major)
        float* ssum = (float*)smem;             // [BM][4]
        float* ssq  = ssum + BM * 4;
        float biasv[NR];
        #pragma unroll
        for (int j = 0; j < NR; ++j) biasv[j] = bias[n0 + wvid * WCOL + j * 16 + r16];
        const unsigned short* resp = res + (size_t)m0 * 256 + wvid * WCOL;
        #pragma unroll
        for (int i = 0; i < MR; ++i)
            #pragma unroll
            for (int r = 0; r < 4; ++r) {
                int row = i * 16 + kg * 4 + r;
                #pragma unroll
                for (int j = 0; j < NR; ++j) {
                    float v = acc[i][j][r] + biasv[j] + bf2f(resp[(size_t)row * 256 + j * 16 + r16]);
                    acc[i][j][r] = v;
                    C[(size_t)(m0 + row) * 256 + wvid * WCOL + j * 16 + r16] = f2bf(v);
                }
            }
        #pragma unroll
        for (int i = 0; i < MR; ++i)
            #pragma unroll
            for (int r = 0; r < 4; ++r) {
                float s = 0.f, sq = 0.f;
                #pragma unroll
                for (int j = 0; j < NR; ++j) { float v = acc[i][j][r]; s += v; sq += v * v; }
                s += __shfl_xor(s, 1); sq += __shfl_xor(sq, 1);
                s += __shfl_xor(s, 2); sq += __shfl_xor(sq, 2);
                s += __shfl_xor(s, 4); sq += __shfl_xor(sq, 4);
                s += __shfl_xor(s, 8); sq += __shfl_xor(sq, 8);
                if (r16 == 0) {
                    int mr = i * 16 + kg * 4 + r;
                    ssum[mr * 4 + wvid] = s;
                    ssq[mr * 4 + wvid] = sq;
                }
            }
        __syncthreads();
        float g2v[NR], b2v[NR];
        #pragma unroll
        for (int j = 0; j < NR; ++j) {
            g2v[j] = g2[wvid * WCOL + j * 16 + r16];
            b2v[j] = b2[wvid * WCOL + j * 16 + r16];
        }
        #pragma unroll
        for (int i = 0; i < MR; ++i)
            #pragma unroll
            for (int r = 0; r < 4; ++r) {
                int mr = i * 16 + kg * 4 + r;
                float sum = ssum[mr * 4] + ssum[mr * 4 + 1] + ssum[mr * 4 + 2] + ssum[mr * 4 + 3];
                float sq  = ssq[mr * 4] + ssq[mr * 4 + 1] + ssq[mr * 4 + 2] + ssq[mr * 4 + 3];
                float mean = sum * (1.f / 256.f);
                float var = sq * (1.f / 256.f) - mean * mean;
                float rstd = rsqrtf(var + 1e-5f);
                int row = m0 + mr;
                size_t lbase = (((size_t)(row >> 6)) * 32 + (size_t)(((row & 63) >> 4) * 8));
                #pragma unroll
                for (int j = 0; j < NR; ++j) {
                    float tv = (acc[i][j][r] - mean) * rstd * g2v[j] + b2v[j];
                    int col = wvid * WCOL + j * 16 + r16;
                    // frag-major store: frag (jj, ks), lane kgc*16+r16r, elem e
                    C2[((lbase + (col >> 5)) * 64 + ((col >> 3) & 3) * 16 + (row & 15)) * 8 + (col & 7)] = f2bf(tv);
                }
            }
    }
}

// ---------------- fused FFN v3c: no tn staging (frag-major tnb), hid-only LDS ----------------
// R6 postmortem: hipcc's __launch_bounds__ 2nd arg behaves as min BLOCKS/CU (CUDA
// semantics). VGPR cap = 512-per-SIMD-pool / (blocks * waves_per_block_per_SIMD):
//   (512,8) -> 512/16 = 32 VGPR (R5, 1.1GB spill); (512,4) -> 512/8 = 64 (R6, 0.5GB
//   spill -- v3b's global B-frag latency needs ~100 live regs); (512,2) -> 512/4 = 128.
// NEVER cap registers below the live set. (512,2) = 2 blocks/CU, 4 waves/SIMD -- same
// achieved occupancy as R4 but without tnL staging + one less barrier per chunk.
__global__ __launch_bounds__(512, 2) void ffn_fused_kernel(
        const unsigned short* __restrict__ tnb,   // frag-major per line: [line][32 frags][64 lanes][8]
        const unsigned short* __restrict__ w1p,   // frag-major, see cvt
        const float* __restrict__ b1,
        const unsigned short* __restrict__ w2p,   // frag-major, see cvt
        const float* __restrict__ b2,
        const unsigned short* __restrict__ yb,    // residual [40960][256] bf16
        float* __restrict__ outT) {               // (B,F,C,H,W) fp32
    __shared__ __align__(16) unsigned short hidL[64 * 256];  // 32KB, frag-major [ks*4+i][lane][8]

    int tid = threadIdx.x;
    int lane = tid & 63, wv = tid >> 6;           // 8 waves
    int r16 = lane & 15, kg = lane >> 4;

    // XCD-aware remap: 640 blocks, 80 per XCD contiguous
    int L = blockIdx.x;
    int blk = (L & 7) * 80 + (L >> 3);
    int m0 = blk * 64;                            // one (bf,h) line of 64 tokens

    const unsigned short* tp = tnb + (size_t)blk * 16384;   // this line's 32 tn fragments

    f32x4 acc2[4][2] = {};                        // out tile: 64 tok x 32 cols (cols wv*32..)

    for (int c = 0; c < 4; ++c) {                 // hid chunks of 256 channels
        // ---- phase 1: hid chunk ch = c*256 + wv*32 + i'*16 + (kg*4+r), tok = j*16+r16 ----
        f32x4 acc[2][4] = {};
        {
            int g = c * 4 + (wv >> 1);
            const unsigned short* ap = w1p + ((size_t)((g * 4 + (wv & 1) * 2) * 8) * 64 + lane) * 8;
            #pragma unroll
            for (int ks = 0; ks < 8; ++ks) {
                bf16x8 a0 = *(const bf16x8*)(ap + (size_t)ks * 512);
                bf16x8 a1 = *(const bf16x8*)(ap + (size_t)4096 + ks * 512);
                bf16x8 b[4];
                #pragma unroll
                for (int j = 0; j < 4; ++j)
                    b[j] = *(const bf16x8*)(tp + ((j * 8 + ks) * 64 + lane) * 8);
                #pragma unroll
                for (int j = 0; j < 4; ++j) {
                    acc[0][j] = __builtin_amdgcn_mfma_f32_16x16x32_bf16(a0, b[j], acc[0][j], 0, 0, 0);
                    acc[1][j] = __builtin_amdgcn_mfma_f32_16x16x32_bf16(a1, b[j], acc[1][j], 0, 0, 0);
                }
            }
        }
        // bias + GELU + pack 4 consecutive ch -> 8B frag-major write (4-way = write floor)
        #pragma unroll
        for (int ip = 0; ip < 2; ++ip) {
            int ch0 = c * 256 + wv * 32 + ip * 16 + kg * 4;
            float bb0 = b1[ch0], bb1 = b1[ch0 + 1], bb2 = b1[ch0 + 2], bb3 = b1[ch0 + 3];
            #pragma unroll
            for (int j = 0; j < 4; ++j) {
                float g0 = gelu_fast(acc[ip][j][0] + bb0);
                float g1 = gelu_fast(acc[ip][j][1] + bb1);
                float g2 = gelu_fast(acc[ip][j][2] + bb2);
                float g3 = gelu_fast(acc[ip][j][3] + bb3);
                uint2 pk;
                pk.x = (unsigned int)f2bf(g0) | ((unsigned int)f2bf(g1) << 16);
                pk.y = (unsigned int)f2bf(g2) | ((unsigned int)f2bf(g3) << 16);
                unsigned int hb = (((unsigned int)(wv * 4 + j) * 64 +
                                    (ip * 2 + (kg >> 1)) * 16 + r16) << 4) + ((kg & 1) << 3);
                *(uint2*)((char*)hidL + hb) = pk;
            }
        }
        __syncthreads();
        // ---- phase 2: acc2 += hid_chunk @ w2^T (A from LDS linear, B from w2p L2 stream) ----
        {
            const unsigned short* bp0 = w2p + ((size_t)((wv * 2) * 32 + c * 8) * 64 + lane) * 8;
            const unsigned short* bp1 = w2p + ((size_t)((wv * 2 + 1) * 32 + c * 8) * 64 + lane) * 8;
            #pragma unroll
            for (int ks = 0; ks < 8; ++ks) {
                bf16x8 a[4];
                #pragma unroll
                for (int i = 0; i < 4; ++i)
                    a[i] = *(const bf16x8*)&hidL[((ks * 4 + i) * 64 + lane) * 8];
                bf16x8 b0 = *(const bf16x8*)(bp0 + (size_t)ks * 512);
                bf16x8 b1v = *(const bf16x8*)(bp1 + (size_t)ks * 512);
                #pragma unroll
                for (int i = 0; i < 4; ++i) {
                    acc2[i][0] = __builtin_amdgcn_mfma_f32_16x16x32_bf16(a[i], b0, acc2[i][0], 0, 0, 0);
                    acc2[i][1] = __builtin_amdgcn_mfma_f32_16x16x32_bf16(a[i], b1v, acc2[i][1], 0, 0, 0);
                }
            }
        }
        __syncthreads();
    }

    // ---- epilogue: + b2 + yb residual, fp32 transposed store (hidL dead -> reuse as fl) ----
    float* fl = (float*)hidL;                     // [64 tokens][64 ch] fp32, XOR col swizzle (16KB)
    int bfi = m0 >> 12;
    int hh = (m0 >> 6) & 63;
    #pragma unroll
    for (int p = 0; p < 4; ++p) {                 // channel groups of 64 = waves {2p, 2p+1}
        __syncthreads();
        if ((wv >> 1) == p) {
            #pragma unroll
            for (int i = 0; i < 4; ++i)
                #pragma unroll
                for (int j = 0; j < 2; ++j)
                    #pragma unroll
                    for (int r = 0; r < 4; ++r) {
                        int ml = i * 16 + kg * 4 + r;            // token within line
                        int nl = (wv & 1) * 32 + j * 16 + r16;   // channel within group
                        int n = p * 64 + nl;
                        float v = acc2[i][j][r] + b2[n] + bf2f(yb[(size_t)(m0 + ml) * 256 + n]);
                        fl[ml * 64 + (nl ^ ml)] = v;
                    }
        }
        __syncthreads();
        for (int r = wv; r < 64; r += 8) {
            outT[(size_t)bfi * 1048576 + (size_t)(p * 64 + r) * 4096 +
                 (size_t)hh * 64 + lane] = fl[lane * 64 + (r ^ lane)];
        }
    }
}

// ---------------- attention (both directions, one launch): per (dir, b, head, line) ----------------
__global__ __launch_bounds__(256) void attn_kernel(const unsigned short* __restrict__ qkvH,
                                                   const unsigned short* __restrict__ qkvV,
                                                   unsigned short* __restrict__ ao) {
    __shared__ unsigned short qL[5 * 1024], kL[5 * 1024], vL[5 * 1024];
    __shared__ float sL[25];
    int g = blockIdx.x;
    int vertical = g >> 10;
    const unsigned short* qkv = vertical ? qkvV : qkvH;
    int lw = g & 63;
    int head = (g >> 6) & 7;
    int b = (g >> 9) & 1;
    int tid = threadIdx.x;
    for (int c = tid; c < 640; c += 256) {
        int f = c >> 7, rem = c & 127;
        int pos = rem >> 1, d0 = (rem & 1) * 8;
        size_t n = (size_t)b * 20480 + (size_t)f * 4096 +
                   (vertical ? (pos * 64 + lw) : (lw * 64 + pos));
        size_t src = n * 384 + head * 16 + d0;
        *(uint4*)&qL[c * 8] = *(const uint4*)&qkv[src];
        *(uint4*)&kL[c * 8] = *(const uint4*)&qkv[src + 128];
        *(uint4*)&vL[c * 8] = *(const uint4*)&qkv[src + 256];
    }
    __syncthreads();
    int lane = tid & 63, wwv = tid >> 6;
    for (int p = wwv; p < 25; p += 4) {
        int qf = p / 5, kf = p - qf * 5;
        float acc = 0.f;
        const unsigned short* qp = &qL[qf * 1024 + lane * 16];
        const unsigned short* kp = &kL[kf * 1024 + lane * 16];
        #pragma unroll
        for (int t = 0; t < 16; ++t) acc += bf2f(qp[t]) * bf2f(kp[t]);
        for (int off = 32; off; off >>= 1) acc += __shfl_down(acc, off);
        if (lane == 0) sL[p] = acc * 0.03125f;   // 1/sqrt(1024)
    }
    __syncthreads();
    if (tid < 5) {
        float mx = -1e30f;
        for (int kf = 0; kf < 5; ++kf) mx = fmaxf(mx, sL[tid * 5 + kf]);
        float e[5], sum = 0.f;
        for (int kf = 0; kf < 5; ++kf) { e[kf] = expf(sL[tid * 5 + kf] - mx); sum += e[kf]; }
        float inv = 1.f / sum;
        for (int kf = 0; kf < 5; ++kf) sL[tid * 5 + kf] = e[kf] * inv;
    }
    __syncthreads();
    int coff = vertical ? 128 : 0;
    for (int c = tid; c < 640; c += 256) {
        int qf = c >> 7, rem = c & 127;
        int pos = rem >> 1, d0 = (rem & 1) * 8;
        float accv[8] = {};
        #pragma unroll
        for (int kf = 0; kf < 5; ++kf) {
            float w = sL[qf * 5 + kf];
            const unsigned short* vp = &vL[kf * 1024 + rem * 8];
            #pragma unroll
            for (int e = 0; e < 8; ++e) accv[e] += w * bf2f(vp[e]);
        }
        unsigned short pk[8];
        #pragma unroll
        for (int e = 0; e < 8; ++e) pk[e] = f2bf(accv[e]);
        size_t n = (size_t)b * 20480 + (size_t)qf * 4096 +
                   (vertical ? (pos * 64 + lw) : (lw * 64 + pos));
        *(uint4*)&ao[n * 256 + coff + head * 16 + d0] = *(const uint4*)pk;
    }
}

extern "C" void kernel_launch(void* const* d_in, const int* in_sizes, int n_in,
                              void* d_out, int out_size, void* d_ws, size_t ws_size,
                              hipStream_t stream) {
    (void)in_sizes; (void)n_in; (void)out_size; (void)ws_size;
    const float* x    = (const float*)d_in[0];
    const float* ln1g = (const float*)d_in[1];
    const float* ln1b = (const float*)d_in[2];
    const float* wh   = (const float*)d_in[3];
    const float* bh   = (const float*)d_in[4];
    const float* wv   = (const float*)d_in[5];
    const float* bv   = (const float*)d_in[6];
    const float* wf   = (const float*)d_in[7];
    const float* bfp  = (const float*)d_in[8];
    const float* ln2g = (const float*)d_in[9];
    const float* ln2b = (const float*)d_in[10];
    const float* w1   = (const float*)d_in[11];
    const float* b1   = (const float*)d_in[12];
    const float* w2   = (const float*)d_in[13];
    const float* b2   = (const float*)d_in[14];
    float* out = (float*)d_out;
    char* ws = (char*)d_ws;

    // workspace layout
    unsigned short* whb = (unsigned short*)(ws + 0);
    unsigned short* wvb = (unsigned short*)(ws + 98304);
    unsigned short* wfb = (unsigned short*)(ws + 196608);
    unsigned short* w1b = (unsigned short*)(ws + 327680);    // w1p frag-major, 512KB
    unsigned short* w2b = (unsigned short*)(ws + 851968);    // w2p frag-major, 512KB
    const size_t off = 1572864;
    unsigned short* tnb  = (unsigned short*)(ws + off);                    // 21.0 MB (frag-major)
    unsigned short* xt   = (unsigned short*)(ws + off + 20971520ull);      // 21.0 MB
    unsigned short* qkvh = (unsigned short*)(ws + off + 41943040ull);      // 31.5 MB
    unsigned short* qkvv = (unsigned short*)(ws + off + 73400320ull);      // 31.5 MB
    unsigned short* ao   = (unsigned short*)(ws + off + 104857600ull);     // 21.0 MB
    unsigned short* yb   = (unsigned short*)(ws + off + 125829120ull);     // 21.0 MB

    cvt_all_kernel<<<896, 256, 0, stream>>>(wh, wv, wf, w1, w2, whb, wvb, wfb, w1b, w2b);

    // fused LN1 + QKV (both halves): writes xt, qkvh, qkvv
    ln1qkv_kernel<<<640, 256, 0, stream>>>(x, ln1g, ln1b, whb, bh, wvb, bv, xt, qkvh, qkvv);

    attn_kernel<<<2048, 256, 0, stream>>>(qkvh, qkvv, ao);

    // proj + residual + LN2 (fused): yb = ao@wf^T + bf + x ; tnb = LN2(yb) [frag-major]
    gemm_t<32, 256, 4, 4><<<dim3(1, 1280), 256, 0, stream>>>(ao, 256, wfb, bfp, yb, 256, xt, nullptr,
                                                             256, ln2g, ln2b, tnb);

    // fused FFN1+FFN2: out = (yb + gelu(tn@w1p+b1)@w2p + b2) -> (B,F,C,H,W) fp32
    ffn_fused_kernel<<<640, 512, 0, stream>>>(tnb, w1b, b1, w2b, b2, yb, out);
}

// Round 8
// 282.165 us; speedup vs baseline: 2.1164x; 1.0726x over previous
//
#include <hip/hip_runtime.h>
#include <cstdint>
#include <cmath>

// Problem constants: B=2, F=5, C=256, H=64, W=64, HN=8, hd=16
// Token layout: n = (b*5+f)*4096 + h*64 + w, N = 40960 tokens, channels-last.

typedef __bf16 bf16x8 __attribute__((ext_vector_type(8)));
typedef float f32x4 __attribute__((ext_vector_type(4)));

__device__ __forceinline__ unsigned short f2bf(float f) {
    union { float f; unsigned int u; } v; v.f = f;
    unsigned int r = (v.u + 0x7fffu + ((v.u >> 16) & 1u)) >> 16;
    return (unsigned short)r;
}
__device__ __forceinline__ float bf2f(unsigned short h) {
    union { unsigned int u; float f; } v; v.u = ((unsigned int)h) << 16;
    return v.f;
}
// tanh-form GELU, fully inline
__device__ __forceinline__ float gelu_fast(float x) {
    float z2 = 2.8853900817779268f * x * (0.7978845608028654f + 0.0356774081363001f * x * x);
    float u = __builtin_amdgcn_exp2f(z2);
    return x - x * __builtin_amdgcn_rcpf(1.0f + u);
}

// async global->LDS, 16B per lane; LDS dest = wave-uniform base + lane*16
__device__ __forceinline__ void gld16(const unsigned short* g, unsigned short* l) {
    __builtin_amdgcn_global_load_lds(
        (const __attribute__((address_space(1))) void*)g,
        (__attribute__((address_space(3))) void*)l, 16, 0, 0);
}

// ---------------- weight convert: wh/wv/wf row-major bf16; w1/w2 MFMA-fragment-major ----------------
// R3 postmortem: per-lane weight-fragment loads (16-row stride-512B scatter) were the FFN
// latency killer. w1p/w2p are packed so each fragment is a CONTIGUOUS 1KB block: lane l's
// 16B at [frag*1024 + l*16]. One coalesced wave-load per fragment, pure L2 streaming.
//   w1p frag id: ((g*4 + fi)*8 + ks)  g=hid-ch/64, fi=16-row group, ks=k/32  (row=g*64+fi*16+r16, k=ks*32+kg*8)
//   w2p frag id: (cg*32 + ksg)        cg=outcol/16, ksg=k/32                (row=cg*16+r16,      k=ksg*32+kg*8)
__global__ __launch_bounds__(256) void cvt_all_kernel(
        const float* __restrict__ wh, const float* __restrict__ wv,
        const float* __restrict__ wf, const float* __restrict__ w1,
        const float* __restrict__ w2,
        unsigned short* __restrict__ whb, unsigned short* __restrict__ wvb,
        unsigned short* __restrict__ wfb, unsigned short* __restrict__ w1b,
        unsigned short* __restrict__ w2b) {
    int i = blockIdx.x * 256 + threadIdx.x;   // grid covers 229376 exactly
    if (i < 163840) {
        const float* s; unsigned short* d; int j;
        if (i < 49152)      { s = wh; d = whb; j = i; }
        else if (i < 98304) { s = wv; d = wvb; j = i - 49152; }
        else                { s = wf; d = wfb; j = i - 98304; }
        d[j] = f2bf(s[j]);
    } else if (i < 196608) {
        int t = i - 163840;                   // 32768 threads x 8 elements
        int lane = t & 63, ks = (t >> 6) & 7, fi = (t >> 9) & 3, g = t >> 11;
        int row = g * 64 + fi * 16 + (lane & 15);
        int k0 = ks * 32 + (lane >> 4) * 8;
        const float* s = w1 + (size_t)row * 256 + k0;
        unsigned short o[8];
        #pragma unroll
        for (int e = 0; e < 8; ++e) o[e] = f2bf(s[e]);
        *(uint4*)&w1b[(size_t)t * 8] = *(const uint4*)o;
    } else {
        int u = i - 196608;                   // 32768 threads x 8 elements
        int lane = u & 63, ksg = (u >> 6) & 31, cg = u >> 11;
        int row = cg * 16 + (lane & 15);
        int k0 = ksg * 32 + (lane >> 4) * 8;
        const float* s = w2 + (size_t)row * 1024 + k0;
        unsigned short o[8];
        #pragma unroll
        for (int e = 0; e < 8; ++e) o[e] = f2bf(s[e]);
        *(uint4*)&w2b[(size_t)u * 8] = *(const uint4*)o;
    }
}

// ---------------- fused LN1 + QKV(h&v): one block per (bf, h) line (64 tokens) ----------------
// R7: x-read vectorized float4 (was scalar 4B/lane -- Common-mistake #2). Thread t loads
// tokens wq4..wq4+3 for channels cgr*16..+16; psum widened to 16 groups.
__global__ __launch_bounds__(256) void ln1qkv_kernel(
        const float* __restrict__ x,
        const float* __restrict__ g, const float* __restrict__ bta,
        const unsigned short* __restrict__ whb, const float* __restrict__ bh,
        const unsigned short* __restrict__ wvb, const float* __restrict__ bv,
        unsigned short* __restrict__ xt,
        unsigned short* __restrict__ qkvh, unsigned short* __restrict__ qkvv) {
    __shared__ __align__(16) unsigned short At[64 * 264];   // 33792 B, [token][ch] padded
    __shared__ __align__(16) unsigned short Bs[128 * 64];   // 16384 B, one BK=64 B-tile
    __shared__ float psum[16][64], psq[16][64];             // 8192 B
    __shared__ float meanL[64], rstdL[64];
    __shared__ float gg[256], bb[256];

    int bx = blockIdx.x;
    int bf = bx >> 6, h = bx & 63;
    size_t base = (size_t)bf * 1048576 + (size_t)h * 64;
    int tid = threadIdx.x;
    int wq4 = (tid & 15) * 4;       // token base (w): 0,4,..,60
    int cgr = tid >> 4;             // channel group 0..15 (16 channels each)
    float s0 = 0.f, s1 = 0.f, s2 = 0.f, s3 = 0.f;
    float q0 = 0.f, q1 = 0.f, q2 = 0.f, q3 = 0.f;
    for (int k = 0; k < 16; ++k) {
        int c = cgr * 16 + k;
        float4 v = *(const float4*)&x[base + (size_t)c * 4096 + wq4];
        s0 += v.x; q0 += v.x * v.x;
        s1 += v.y; q1 += v.y * v.y;
        s2 += v.z; q2 += v.z * v.z;
        s3 += v.w; q3 += v.w * v.w;
        At[(wq4 + 0) * 264 + c] = f2bf(v.x);
        At[(wq4 + 1) * 264 + c] = f2bf(v.y);
        At[(wq4 + 2) * 264 + c] = f2bf(v.z);
        At[(wq4 + 3) * 264 + c] = f2bf(v.w);
    }
    psum[cgr][wq4 + 0] = s0; psq[cgr][wq4 + 0] = q0;
    psum[cgr][wq4 + 1] = s1; psq[cgr][wq4 + 1] = q1;
    psum[cgr][wq4 + 2] = s2; psq[cgr][wq4 + 2] = q2;
    psum[cgr][wq4 + 3] = s3; psq[cgr][wq4 + 3] = q3;
    gg[tid] = g[tid]; bb[tid] = bta[tid];
    __syncthreads();
    if (tid < 64) {
        float ss = 0.f, qq = 0.f;
        #pragma unroll
        for (int gr = 0; gr < 16; ++gr) { ss += psum[gr][tid]; qq += psq[gr][tid]; }
        float mean = ss * (1.f / 256.f);
        float var = qq * (1.f / 256.f) - mean * mean;
        meanL[tid] = mean;
        rstdL[tid] = rsqrtf(var + 1e-5f);
    }
    __syncthreads();
    int n0g = bf * 4096 + h * 64;
    for (int t = 0; t < 8; ++t) {
        int idx = t * 256 + tid;
        int tok = idx >> 5, cc = idx & 31;
        unsigned short raw[8];
        *(uint4*)raw = *(const uint4*)&At[tok * 264 + cc * 8];
        *(uint4*)&xt[(size_t)(n0g + tok) * 256 + cc * 8] = *(const uint4*)raw;
        float mean = meanL[tok], rstd = rstdL[tok];
        unsigned short nm[8];
        #pragma unroll
        for (int e = 0; e < 8; ++e) {
            int ch = cc * 8 + e;
            nm[e] = f2bf((bf2f(raw[e]) - mean) * rstd * gg[ch] + bb[ch]);
        }
        *(uint4*)&At[tok * 264 + cc * 8] = *(const uint4*)nm;
    }
    __syncthreads();

    int lane = tid & 63, wvid = tid >> 6;
    int r16 = lane & 15, kg = lane >> 4;
    int srow = wvid * 8 + (lane >> 3);
    int segg = (lane & 7) ^ (lane >> 3);
    unsigned short* lB = Bs + wvid * 512;
    for (int t = 0; t < 6; ++t) {
        const unsigned short* Wt; const float* bias; unsigned short* dst; int ot, aoff;
        if (t < 3) { Wt = whb + t * 16384;       bias = bh + t * 128;       dst = qkvh; ot = t * 128;       aoff = 0; }
        else       { Wt = wvb + (t - 3) * 16384; bias = bv + (t - 3) * 128; dst = qkvv; ot = (t - 3) * 128; aoff = 128; }
        f32x4 acc[4][2] = {};
        for (int kk = 0; kk < 2; ++kk) {
            const unsigned short* pB = Wt + (size_t)srow * 128 + kk * 64 + segg * 8;
            #pragma unroll
            for (int i = 0; i < 4; ++i)
                gld16(pB + (size_t)i * 32 * 128, lB + i * 2048);
            __syncthreads();
            #pragma unroll
            for (int tt = 0; tt < 2; ++tt) {
                int ka = aoff + kk * 64 + (tt * 4 + kg) * 8;
                int ss = ((tt * 4 + kg) ^ (r16 & 7)) * 8;
                bf16x8 af[4], bfr[2];
                #pragma unroll
                for (int i = 0; i < 4; ++i)
                    af[i] = *(const bf16x8*)&At[(i * 16 + r16) * 264 + ka];
                #pragma unroll
                for (int j = 0; j < 2; ++j)
                    bfr[j] = *(const bf16x8*)&Bs[(wvid * 32 + j * 16 + r16) * 64 + ss];
                #pragma unroll
                for (int i = 0; i < 4; ++i)
                    #pragma unroll
                    for (int j = 0; j < 2; ++j)
                        acc[i][j] = __builtin_amdgcn_mfma_f32_16x16x32_bf16(af[i], bfr[j], acc[i][j], 0, 0, 0);
            }
            __syncthreads();
        }
        float biasv[2];
        #pragma unroll
        for (int j = 0; j < 2; ++j) biasv[j] = bias[wvid * 32 + j * 16 + r16];
        #pragma unroll
        for (int i = 0; i < 4; ++i)
            #pragma unroll
            for (int j = 0; j < 2; ++j)
                #pragma unroll
                for (int r = 0; r < 4; ++r) {
                    int m = i * 16 + kg * 4 + r;
                    int nc = ot + wvid * 32 + j * 16 + r16;
                    dst[(size_t)(n0g + m) * 384 + nc] = f2bf(acc[i][j][r] + biasv[j]);
                }
    }
}

// ---------------- templated MFMA GEMM (only MODE 4 = proj+LN2 instantiated) ----------------
// MODE 4 writes C2 (tn) in FRAGMENT-MAJOR layout (R4): tnb[((line*32 + jj*8 + ks)*64
// + kgc*16 + r16r)*8 + e] holds tn[line*64 + jj*16 + r16r][ks*32 + kgc*8 + e], so the FFN
// kernel can stage it to LDS with async gld16 (lane-linear 1KB wave-loads).
// NOTE: every acc[] subscript must be compile-time constant (dynamic indexing
// spills the whole accumulator array to scratch -- R8 postmortem: 1.36 GB scratch traffic).
template<int BM, int BN, int MODE, int MINW>
__global__ __launch_bounds__(256, MINW) void gemm_t(
        const unsigned short* __restrict__ A, int lda,
        const unsigned short* __restrict__ B,
        const float* __restrict__ bias,
        unsigned short* __restrict__ C, int ldc,
        const unsigned short* __restrict__ res,
        float* __restrict__ outT,
        int K,
        const float* __restrict__ g2, const float* __restrict__ b2,
        unsigned short* __restrict__ C2) {
    constexpr int WCOL = BN / 4;        // cols per wave
    constexpr int MR = BM / 16;         // 16-row fragments per wave
    constexpr int NR = WCOL / 16;       // 16-col fragments per wave
    constexpr int AG = BM / 32;         // A gld16 per wave per K-step
    constexpr int BG = BN / 32;         // B gld16 per wave per K-step
    __shared__ __align__(16) unsigned char smem[(BM + BN) * 128];
    unsigned short* As = (unsigned short*)smem;
    unsigned short* Bs = (unsigned short*)(smem + BM * 128);

    int tid = threadIdx.x;
    int lane = tid & 63, wvid = tid >> 6;
    int r16 = lane & 15, kg = lane >> 4;

    // XCD-aware remap (total blocks divisible by 8 in all configs)
    int nx = gridDim.x;
    int L = blockIdx.y * nx + blockIdx.x;
    int T = nx * gridDim.y;
    int newL = (T & 7) ? L : ((L & 7) * (T >> 3) + (L >> 3));
    int nt = newL % nx, mt = newL / nx;
    int m0 = mt * BM, n0 = nt * BN;

    int srow = wvid * 8 + (lane >> 3);
    int segg = (lane & 7) ^ (lane >> 3);
    const unsigned short* pA = A + (size_t)(m0 + srow) * lda + segg * 8;
    const unsigned short* pB = B + (size_t)(n0 + srow) * K + segg * 8;
    unsigned short* lA = As + wvid * 512;
    unsigned short* lB = Bs + wvid * 512;

    f32x4 acc[MR][NR] = {};
    for (int k0 = 0; k0 < K; k0 += 64) {
        #pragma unroll
        for (int i = 0; i < AG; ++i)
            gld16(pA + (size_t)i * 32 * lda, lA + i * 2048);
        #pragma unroll
        for (int i = 0; i < BG; ++i)
            gld16(pB + (size_t)i * 32 * K, lB + i * 2048);
        pA += 64; pB += 64;
        __syncthreads();
        #pragma unroll
        for (int t = 0; t < 2; ++t) {
            bf16x8 af[MR], bfr[NR];
            int ss = ((t * 4 + kg) ^ (r16 & 7)) * 8;
            #pragma unroll
            for (int i = 0; i < MR; ++i)
                af[i] = *(const bf16x8*)&As[(i * 16 + r16) * 64 + ss];
            #pragma unroll
            for (int j = 0; j < NR; ++j)
                bfr[j] = *(const bf16x8*)&Bs[(wvid * WCOL + j * 16 + r16) * 64 + ss];
            #pragma unroll
            for (int i = 0; i < MR; ++i)
                #pragma unroll
                for (int j = 0; j < NR; ++j)
                    acc[i][j] = __builtin_amdgcn_mfma_f32_16x16x32_bf16(af[i], bfr[j], acc[i][j], 0, 0, 0);
        }
        __syncthreads();
    }

    if constexpr (MODE == 4) {
        // BM=32, BN=256: y = acc + bias + res -> C (yb); row LN over 256 cols -> C2 (tn, frag-major)
        float* ssum = (float*)smem;             // [BM][4]
        float* ssq  = ssum + BM * 4;
        float biasv[NR];
        #pragma unroll
        for (int j = 0; j < NR; ++j) biasv[j] = bias[n0 + wvid * WCOL + j * 16 + r16];
        const unsigned short* resp = res + (size_t)m0 * 256 + wvid * WCOL;
        #pragma unroll
        for (int i = 0; i < MR; ++i)
            #pragma unroll
            for (int r = 0; r < 4; ++r) {
                int row = i * 16 + kg * 4 + r;
                #pragma unroll
                for (int j = 0; j < NR; ++j) {
                    float v = acc[i][j][r] + biasv[j] + bf2f(resp[(size_t)row * 256 + j * 16 + r16]);
                    acc[i][j][r] = v;
                    C[(size_t)(m0 + row) * 256 + wvid * WCOL + j * 16 + r16] = f2bf(v);
                }
            }
        #pragma unroll
        for (int i = 0; i < MR; ++i)
            #pragma unroll
            for (int r = 0; r < 4; ++r) {
                float s = 0.f, sq = 0.f;
                #pragma unroll
                for (int j = 0; j < NR; ++j) { float v = acc[i][j][r]; s += v; sq += v * v; }
                s += __shfl_xor(s, 1); sq += __shfl_xor(sq, 1);
                s += __shfl_xor(s, 2); sq += __shfl_xor(sq, 2);
                s += __shfl_xor(s, 4); sq += __shfl_xor(sq, 4);
                s += __shfl_xor(s, 8); sq += __shfl_xor(sq, 8);
                if (r16 == 0) {
                    int mr = i * 16 + kg * 4 + r;
                    ssum[mr * 4 + wvid] = s;
                    ssq[mr * 4 + wvid] = sq;
                }
            }
        __syncthreads();
        float g2v[NR], b2v[NR];
        #pragma unroll
        for (int j = 0; j < NR; ++j) {
            g2v[j] = g2[wvid * WCOL + j * 16 + r16];
            b2v[j] = b2[wvid * WCOL + j * 16 + r16];
        }
        #pragma unroll
        for (int i = 0; i < MR; ++i)
            #pragma unroll
            for (int r = 0; r < 4; ++r) {
                int mr = i * 16 + kg * 4 + r;
                float sum = ssum[mr * 4] + ssum[mr * 4 + 1] + ssum[mr * 4 + 2] + ssum[mr * 4 + 3];
                float sq  = ssq[mr * 4] + ssq[mr * 4 + 1] + ssq[mr * 4 + 2] + ssq[mr * 4 + 3];
                float mean = sum * (1.f / 256.f);
                float var = sq * (1.f / 256.f) - mean * mean;
                float rstd = rsqrtf(var + 1e-5f);
                int row = m0 + mr;
                size_t lbase = (((size_t)(row >> 6)) * 32 + (size_t)(((row & 63) >> 4) * 8));
                #pragma unroll
                for (int j = 0; j < NR; ++j) {
                    float tv = (acc[i][j][r] - mean) * rstd * g2v[j] + b2v[j];
                    int col = wvid * WCOL + j * 16 + r16;
                    // frag-major store: frag (jj, ks), lane kgc*16+r16r, elem e
                    C2[((lbase + (col >> 5)) * 64 + ((col >> 3) & 3) * 16 + (row & 15)) * 8 + (col & 7)] = f2bf(tv);
                }
            }
    }
}

// ---------------- fused FFN v3d: tn staged via async gld16 (frag-major), hid in LDS ----------------
// R7 postmortem: tn B-frags from global per k-step (4 x ~200cy/ks) lost to v2's LDS reads
// (118 vs 103us) -- revert trigger fired. v3d keeps frag-major tnb but stages it to LDS ONCE
// via gld16 (lane-linear 1KB async copies, no reg round-trip, no scattered reads -- fixes
// both of v2's staging costs). Phase-1 B-frags = conflict-free ds_read_b128. LDS 64KB ->
// 2 blocks/CU; (512,2) -> VGPR cap 128 (R7: ~116 live, no spill).
__global__ __launch_bounds__(512, 2) void ffn_fused_kernel(
        const unsigned short* __restrict__ tnb,   // frag-major per line: [line][32 frags][64 lanes][8]
        const unsigned short* __restrict__ w1p,   // frag-major, see cvt
        const float* __restrict__ b1,
        const unsigned short* __restrict__ w2p,   // frag-major, see cvt
        const float* __restrict__ b2,
        const unsigned short* __restrict__ yb,    // residual [40960][256] bf16
        float* __restrict__ outT) {               // (B,F,C,H,W) fp32
    __shared__ __align__(16) unsigned short tnL[64 * 256];   // 32KB, frag-major (gld16-staged)
    __shared__ __align__(16) unsigned short hidL[64 * 256];  // 32KB, frag-major [ks*4+i][lane][8]

    int tid = threadIdx.x;
    int lane = tid & 63, wv = tid >> 6;           // 8 waves
    int r16 = lane & 15, kg = lane >> 4;

    // XCD-aware remap: 640 blocks, 80 per XCD contiguous
    int L = blockIdx.x;
    int blk = (L & 7) * 80 + (L >> 3);
    int m0 = blk * 64;                            // one (bf,h) line of 64 tokens

    // ---- stage tn fragments (32KB) via async gld16: wave wv copies frags wv*4..wv*4+3 ----
    {
        const unsigned short* tp = tnb + (size_t)blk * 16384;
        #pragma unroll
        for (int f = 0; f < 4; ++f) {
            int frag = wv * 4 + f;
            gld16(tp + (size_t)frag * 512 + lane * 8, tnL + frag * 512);
        }
    }
    __syncthreads();

    f32x4 acc2[4][2] = {};                        // out tile: 64 tok x 32 cols (cols wv*32..)

    for (int c = 0; c < 4; ++c) {                 // hid chunks of 256 channels
        // ---- phase 1: hid chunk ch = c*256 + wv*32 + i'*16 + (kg*4+r), tok = j*16+r16 ----
        f32x4 acc[2][4] = {};
        {
            int g = c * 4 + (wv >> 1);
            const unsigned short* ap = w1p + ((size_t)((g * 4 + (wv & 1) * 2) * 8) * 64 + lane) * 8;
            #pragma unroll
            for (int ks = 0; ks < 8; ++ks) {
                bf16x8 a0 = *(const bf16x8*)(ap + (size_t)ks * 512);
                bf16x8 a1 = *(const bf16x8*)(ap + (size_t)4096 + ks * 512);
                bf16x8 b[4];
                #pragma unroll
                for (int j = 0; j < 4; ++j)
                    b[j] = *(const bf16x8*)&tnL[((j * 8 + ks) * 64 + lane) * 8];
                #pragma unroll
                for (int j = 0; j < 4; ++j) {
                    acc[0][j] = __builtin_amdgcn_mfma_f32_16x16x32_bf16(a0, b[j], acc[0][j], 0, 0, 0);
                    acc[1][j] = __builtin_amdgcn_mfma_f32_16x16x32_bf16(a1, b[j], acc[1][j], 0, 0, 0);
                }
            }
        }
        // bias + GELU + pack 4 consecutive ch -> 8B frag-major write (4-way = write floor)
        #pragma unroll
        for (int ip = 0; ip < 2; ++ip) {
            int ch0 = c * 256 + wv * 32 + ip * 16 + kg * 4;
            float bb0 = b1[ch0], bb1 = b1[ch0 + 1], bb2 = b1[ch0 + 2], bb3 = b1[ch0 + 3];
            #pragma unroll
            for (int j = 0; j < 4; ++j) {
                float g0 = gelu_fast(acc[ip][j][0] + bb0);
                float g1 = gelu_fast(acc[ip][j][1] + bb1);
                float g2 = gelu_fast(acc[ip][j][2] + bb2);
                float g3 = gelu_fast(acc[ip][j][3] + bb3);
                uint2 pk;
                pk.x = (unsigned int)f2bf(g0) | ((unsigned int)f2bf(g1) << 16);
                pk.y = (unsigned int)f2bf(g2) | ((unsigned int)f2bf(g3) << 16);
                unsigned int hb = (((unsigned int)(wv * 4 + j) * 64 +
                                    (ip * 2 + (kg >> 1)) * 16 + r16) << 4) + ((kg & 1) << 3);
                *(uint2*)((char*)hidL + hb) = pk;
            }
        }
        __syncthreads();
        // ---- phase 2: acc2 += hid_chunk @ w2^T (A from LDS linear, B from w2p L2 stream) ----
        {
            const unsigned short* bp0 = w2p + ((size_t)((wv * 2) * 32 + c * 8) * 64 + lane) * 8;
            const unsigned short* bp1 = w2p + ((size_t)((wv * 2 + 1) * 32 + c * 8) * 64 + lane) * 8;
            #pragma unroll
            for (int ks = 0; ks < 8; ++ks) {
                bf16x8 a[4];
                #pragma unroll
                for (int i = 0; i < 4; ++i)
                    a[i] = *(const bf16x8*)&hidL[((ks * 4 + i) * 64 + lane) * 8];
                bf16x8 b0 = *(const bf16x8*)(bp0 + (size_t)ks * 512);
                bf16x8 b1v = *(const bf16x8*)(bp1 + (size_t)ks * 512);
                #pragma unroll
                for (int i = 0; i < 4; ++i) {
                    acc2[i][0] = __builtin_amdgcn_mfma_f32_16x16x32_bf16(a[i], b0, acc2[i][0], 0, 0, 0);
                    acc2[i][1] = __builtin_amdgcn_mfma_f32_16x16x32_bf16(a[i], b1v, acc2[i][1], 0, 0, 0);
                }
            }
        }
        __syncthreads();
    }

    // ---- epilogue: + b2 + yb residual, fp32 transposed store (hidL dead -> reuse as fl) ----
    float* fl = (float*)hidL;                     // [64 tokens][64 ch] fp32, XOR col swizzle (16KB)
    int bfi = m0 >> 12;
    int hh = (m0 >> 6) & 63;
    #pragma unroll
    for (int p = 0; p < 4; ++p) {                 // channel groups of 64 = waves {2p, 2p+1}
        __syncthreads();
        if ((wv >> 1) == p) {
            #pragma unroll
            for (int i = 0; i < 4; ++i)
                #pragma unroll
                for (int j = 0; j < 2; ++j)
                    #pragma unroll
                    for (int r = 0; r < 4; ++r) {
                        int ml = i * 16 + kg * 4 + r;            // token within line
                        int nl = (wv & 1) * 32 + j * 16 + r16;   // channel within group
                        int n = p * 64 + nl;
                        float v = acc2[i][j][r] + b2[n] + bf2f(yb[(size_t)(m0 + ml) * 256 + n]);
                        fl[ml * 64 + (nl ^ ml)] = v;
                    }
        }
        __syncthreads();
        for (int r = wv; r < 64; r += 8) {
            outT[(size_t)bfi * 1048576 + (size_t)(p * 64 + r) * 4096 +
                 (size_t)hh * 64 + lane] = fl[lane * 64 + (r ^ lane)];
        }
    }
}

// ---------------- attention (both directions, one launch): per (dir, b, head, line) ----------------
__global__ __launch_bounds__(256) void attn_kernel(const unsigned short* __restrict__ qkvH,
                                                   const unsigned short* __restrict__ qkvV,
                                                   unsigned short* __restrict__ ao) {
    __shared__ unsigned short qL[5 * 1024], kL[5 * 1024], vL[5 * 1024];
    __shared__ float sL[25];
    int g = blockIdx.x;
    int vertical = g >> 10;
    const unsigned short* qkv = vertical ? qkvV : qkvH;
    int lw = g & 63;
    int head = (g >> 6) & 7;
    int b = (g >> 9) & 1;
    int tid = threadIdx.x;
    for (int c = tid; c < 640; c += 256) {
        int f = c >> 7, rem = c & 127;
        int pos = rem >> 1, d0 = (rem & 1) * 8;
        size_t n = (size_t)b * 20480 + (size_t)f * 4096 +
                   (vertical ? (pos * 64 + lw) : (lw * 64 + pos));
        size_t src = n * 384 + head * 16 + d0;
        *(uint4*)&qL[c * 8] = *(const uint4*)&qkv[src];
        *(uint4*)&kL[c * 8] = *(const uint4*)&qkv[src + 128];
        *(uint4*)&vL[c * 8] = *(const uint4*)&qkv[src + 256];
    }
    __syncthreads();
    int lane = tid & 63, wwv = tid >> 6;
    for (int p = wwv; p < 25; p += 4) {
        int qf = p / 5, kf = p - qf * 5;
        float acc = 0.f;
        const unsigned short* qp = &qL[qf * 1024 + lane * 16];
        const unsigned short* kp = &kL[kf * 1024 + lane * 16];
        #pragma unroll
        for (int t = 0; t < 16; ++t) acc += bf2f(qp[t]) * bf2f(kp[t]);
        for (int off = 32; off; off >>= 1) acc += __shfl_down(acc, off);
        if (lane == 0) sL[p] = acc * 0.03125f;   // 1/sqrt(1024)
    }
    __syncthreads();
    if (tid < 5) {
        float mx = -1e30f;
        for (int kf = 0; kf < 5; ++kf) mx = fmaxf(mx, sL[tid * 5 + kf]);
        float e[5], sum = 0.f;
        for (int kf = 0; kf < 5; ++kf) { e[kf] = expf(sL[tid * 5 + kf] - mx); sum += e[kf]; }
        float inv = 1.f / sum;
        for (int kf = 0; kf < 5; ++kf) sL[tid * 5 + kf] = e[kf] * inv;
    }
    __syncthreads();
    int coff = vertical ? 128 : 0;
    for (int c = tid; c < 640; c += 256) {
        int qf = c >> 7, rem = c & 127;
        int pos = rem >> 1, d0 = (rem & 1) * 8;
        float accv[8] = {};
        #pragma unroll
        for (int kf = 0; kf < 5; ++kf) {
            float w = sL[qf * 5 + kf];
            const unsigned short* vp = &vL[kf * 1024 + rem * 8];
            #pragma unroll
            for (int e = 0; e < 8; ++e) accv[e] += w * bf2f(vp[e]);
        }
        unsigned short pk[8];
        #pragma unroll
        for (int e = 0; e < 8; ++e) pk[e] = f2bf(accv[e]);
        size_t n = (size_t)b * 20480 + (size_t)qf * 4096 +
                   (vertical ? (pos * 64 + lw) : (lw * 64 + pos));
        *(uint4*)&ao[n * 256 + coff + head * 16 + d0] = *(const uint4*)pk;
    }
}

extern "C" void kernel_launch(void* const* d_in, const int* in_sizes, int n_in,
                              void* d_out, int out_size, void* d_ws, size_t ws_size,
                              hipStream_t stream) {
    (void)in_sizes; (void)n_in; (void)out_size; (void)ws_size;
    const float* x    = (const float*)d_in[0];
    const float* ln1g = (const float*)d_in[1];
    const float* ln1b = (const float*)d_in[2];
    const float* wh   = (const float*)d_in[3];
    const float* bh   = (const float*)d_in[4];
    const float* wv   = (const float*)d_in[5];
    const float* bv   = (const float*)d_in[6];
    const float* wf   = (const float*)d_in[7];
    const float* bfp  = (const float*)d_in[8];
    const float* ln2g = (const float*)d_in[9];
    const float* ln2b = (const float*)d_in[10];
    const float* w1   = (const float*)d_in[11];
    const float* b1   = (const float*)d_in[12];
    const float* w2   = (const float*)d_in[13];
    const float* b2   = (const float*)d_in[14];
    float* out = (float*)d_out;
    char* ws = (char*)d_ws;

    // workspace layout
    unsigned short* whb = (unsigned short*)(ws + 0);
    unsigned short* wvb = (unsigned short*)(ws + 98304);
    unsigned short* wfb = (unsigned short*)(ws + 196608);
    unsigned short* w1b = (unsigned short*)(ws + 327680);    // w1p frag-major, 512KB
    unsigned short* w2b = (unsigned short*)(ws + 851968);    // w2p frag-major, 512KB
    const size_t off = 1572864;
    unsigned short* tnb  = (unsigned short*)(ws + off);                    // 21.0 MB (frag-major)
    unsigned short* xt   = (unsigned short*)(ws + off + 20971520ull);      // 21.0 MB
    unsigned short* qkvh = (unsigned short*)(ws + off + 41943040ull);      // 31.5 MB
    unsigned short* qkvv = (unsigned short*)(ws + off + 73400320ull);      // 31.5 MB
    unsigned short* ao   = (unsigned short*)(ws + off + 104857600ull);     // 21.0 MB
    unsigned short* yb   = (unsigned short*)(ws + off + 125829120ull);     // 21.0 MB

    cvt_all_kernel<<<896, 256, 0, stream>>>(wh, wv, wf, w1, w2, whb, wvb, wfb, w1b, w2b);

    // fused LN1 + QKV (both halves): writes xt, qkvh, qkvv
    ln1qkv_kernel<<<640, 256, 0, stream>>>(x, ln1g, ln1b, whb, bh, wvb, bv, xt, qkvh, qkvv);

    attn_kernel<<<2048, 256, 0, stream>>>(qkvh, qkvv, ao);

    // proj + residual + LN2 (fused): yb = ao@wf^T + bf + x ; tnb = LN2(yb) [frag-major]
    gemm_t<32, 256, 4, 4><<<dim3(1, 1280), 256, 0, stream>>>(ao, 256, wfb, bfp, yb, 256, xt, nullptr,
                                                             256, ln2g, ln2b, tnb);

    // fused FFN1+FFN2: out = (yb + gelu(tn@w1p+b1)@w2p + b2) -> (B,F,C,H,W) fp32
    ffn_fused_kernel<<<640, 512, 0, stream>>>(tnb, w1b, b1, w2b, b2, yb, out);
}